// Round 1
// baseline (906.791 us; speedup 1.0000x reference)
//
#include <hip/hip_runtime.h>
#include <hip/hip_bf16.h>
#include <float.h>

#define T_LEN 2048
#define DM    1024
#define NB    128
#define NEGC  (-1e9f)

// ---------------- wave-wide helpers (wave64) ----------------
__device__ __forceinline__ float wred_max(float v) {
#pragma unroll
  for (int o = 32; o > 0; o >>= 1) v = fmaxf(v, __shfl_xor(v, o, 64));
  return v;
}
__device__ __forceinline__ float wred_sum(float v) {
#pragma unroll
  for (int o = 32; o > 0; o >>= 1) v += __shfl_xor(v, o, 64);
  return v;
}

// ---------------- generic fp32 GEMM: C(M,N) = A(M,K) @ B(K,N) ----------------
// 64x64 tile, BK=16, 256 threads, 4x4 microtile.
__global__ __launch_bounds__(256) void gemm_f32(const float* __restrict__ A,
                                                const float* __restrict__ B,
                                                float* __restrict__ C,
                                                int M, int N, int K) {
  __shared__ float As[16][68];  // [k][m], padded: rows 16B-aligned
  __shared__ float Bs[16][68];  // [k][n]
  const int tid = threadIdx.x;
  const int tx = tid & 15, ty = tid >> 4;
  const int row0 = blockIdx.y * 64, col0 = blockIdx.x * 64;

  const int am = tid >> 2;          // 0..63
  const int ak = (tid & 3) * 4;     // 0,4,8,12
  const int br = tid >> 4;          // 0..15
  const int bc = (tid & 15) * 4;    // 0..60

  float acc[4][4] = {};
  for (int k0 = 0; k0 < K; k0 += 16) {
    float4 av = *(const float4*)&A[(size_t)(row0 + am) * K + k0 + ak];
    As[ak + 0][am] = av.x; As[ak + 1][am] = av.y;
    As[ak + 2][am] = av.z; As[ak + 3][am] = av.w;
    float4 bv = *(const float4*)&B[(size_t)(k0 + br) * N + col0 + bc];
    *(float4*)&Bs[br][bc] = bv;
    __syncthreads();
#pragma unroll
    for (int kk = 0; kk < 16; kk++) {
      float4 a = *(const float4*)&As[kk][ty * 4];
      float4 b = *(const float4*)&Bs[kk][tx * 4];
      acc[0][0] += a.x * b.x; acc[0][1] += a.x * b.y; acc[0][2] += a.x * b.z; acc[0][3] += a.x * b.w;
      acc[1][0] += a.y * b.x; acc[1][1] += a.y * b.y; acc[1][2] += a.y * b.z; acc[1][3] += a.y * b.w;
      acc[2][0] += a.z * b.x; acc[2][1] += a.z * b.y; acc[2][2] += a.z * b.z; acc[2][3] += a.z * b.w;
      acc[3][0] += a.w * b.x; acc[3][1] += a.w * b.y; acc[3][2] += a.w * b.z; acc[3][3] += a.w * b.w;
    }
    __syncthreads();
  }
#pragma unroll
  for (int i = 0; i < 4; i++) {
    float4 o = make_float4(acc[i][0], acc[i][1], acc[i][2], acc[i][3]);
    *(float4*)&C[(size_t)(row0 + ty * 4 + i) * N + col0 + tx * 4] = o;
  }
}

// ---------------- transpose k (T, H*D) -> kT (H*D, T) ----------------
__global__ void transpose_k(const float* __restrict__ k, float* __restrict__ kT) {
  __shared__ float tile[32][33];
  const int c0 = blockIdx.x * 32, t0 = blockIdx.y * 32;
  const int tx = threadIdx.x, ty = threadIdx.y;  // (32, 8)
#pragma unroll
  for (int i = 0; i < 32; i += 8)
    tile[ty + i][tx] = k[(size_t)(t0 + ty + i) * DM + c0 + tx];
  __syncthreads();
#pragma unroll
  for (int i = 0; i < 32; i += 8)
    kT[(size_t)(c0 + ty + i) * T_LEN + t0 + tx] = tile[tx][ty + i];
}

// ---------------- compressed K/V: kc[h,n,:] = vec(k block) @ Wck ----------------
// grid (NB/8, H), 256 threads; each wave handles 2 blocks, K phase then V phase.
__global__ __launch_bounds__(256) void compress_kv(
    const float* __restrict__ k, const float* __restrict__ v,
    const float* __restrict__ Wck, const float* __restrict__ Wcv,
    float* __restrict__ kc, float* __restrict__ vc) {
  __shared__ float sb[4][2][1024];
  const int h = blockIdx.y;
  const int w = threadIdx.x >> 6, lane = threadIdx.x & 63;
  const int n0 = blockIdx.x * 8 + w * 2;

  // K phase
#pragma unroll
  for (int m = 0; m < 2; m++)
#pragma unroll 4
    for (int i = 0; i < 16; i++)
      sb[w][m][i * 64 + lane] = k[(size_t)((n0 + m) * 16 + i) * DM + h * 64 + lane];
  float a0 = 0.f, a1 = 0.f;
#pragma unroll 4
  for (int i = 0; i < 1024; i++) {
    float wk = Wck[i * 64 + lane];
    a0 += sb[w][0][i] * wk;
    a1 += sb[w][1][i] * wk;
  }
  kc[h * 8192 + n0 * 64 + lane] = a0;
  kc[h * 8192 + (n0 + 1) * 64 + lane] = a1;

  // V phase (reuse LDS; same-wave in-order LDS keeps this safe)
#pragma unroll
  for (int m = 0; m < 2; m++)
#pragma unroll 4
    for (int i = 0; i < 16; i++)
      sb[w][m][i * 64 + lane] = v[(size_t)((n0 + m) * 16 + i) * DM + h * 64 + lane];
  a0 = 0.f; a1 = 0.f;
#pragma unroll 4
  for (int i = 0; i < 1024; i++) {
    float wv = Wcv[i * 64 + lane];
    a0 += sb[w][0][i] * wv;
    a1 += sb[w][1][i] * wv;
  }
  vc[h * 8192 + n0 * 64 + lane] = a0;
  vc[h * 8192 + (n0 + 1) * 64 + lane] = a1;
}

// ---------------- gates: softmax(mean_h q[t,h,:] @ Wg + bg) ----------------
// one wave per t; 4 waves per block.
__global__ __launch_bounds__(256) void gates_k(const float* __restrict__ q,
                                               const float* __restrict__ Wg,
                                               const float* __restrict__ bg,
                                               float* __restrict__ gates) {
  const int w = threadIdx.x >> 6, lane = threadIdx.x & 63;
  const int t = blockIdx.x * 4 + w;
  float m = 0.f;
#pragma unroll
  for (int h = 0; h < 16; h++) m += q[(size_t)t * DM + h * 64 + lane];
  m *= (1.f / 16.f);
  float g0 = wred_sum(m * Wg[lane * 3 + 0]);
  float g1 = wred_sum(m * Wg[lane * 3 + 1]);
  float g2 = wred_sum(m * Wg[lane * 3 + 2]);
  if (lane == 0) {
    g0 += bg[0]; g1 += bg[1]; g2 += bg[2];
    float mx = fmaxf(g0, fmaxf(g1, g2));
    float e0 = __expf(g0 - mx), e1 = __expf(g1 - mx), e2 = __expf(g2 - mx);
    float inv = 1.f / (e0 + e1 + e2);
    gates[t * 3 + 0] = e0 * inv;
    gates[t * 3 + 1] = e1 * inv;
    gates[t * 3 + 2] = e2 * inv;
  }
}

// ---------------- fused NSA attention: all three branches + gating ----------------
// grid (T/32, H), 256 threads; one wave per query, 8 queries per wave.
__global__ __launch_bounds__(256) void nsa_attn(
    const float* __restrict__ q, const float* __restrict__ kT,
    const float* __restrict__ v, const float* __restrict__ kc,
    const float* __restrict__ vc, const float* __restrict__ gates,
    float* __restrict__ outf) {
  __shared__ float kc_s[NB * 64];           // fp32 (selection-critical)
  __shared__ __hip_bfloat16 vc_s[NB * 64];  // bf16 (only scales out_c, ~1e-3 final)
  __shared__ float qb[4][64];
  __shared__ float pb[4][128];
  __shared__ float ps[4][64];
  __shared__ float pw[4][64];

  const int h = blockIdx.y;
  const int t0 = blockIdx.x * 32;
  const int tid = threadIdx.x;
  const int w = tid >> 6;
  const int lane = tid & 63;

  for (int idx = tid; idx < NB * 64; idx += 256) {
    kc_s[idx] = kc[h * (NB * 64) + idx];
    vc_s[idx] = __float2bfloat16(vc[h * (NB * 64) + idx]);
  }
  __syncthreads();

  const float* kTh = kT + (size_t)h * 64 * T_LEN;
  const float* vh  = v + h * 64;

  for (int i = 0; i < 8; i++) {
    const int t = t0 + w * 8 + i;
    const int count = t >> 4;  // number of fully-past blocks
    qb[w][lane] = q[(size_t)t * DM + h * 64 + lane];

    // ---- compressed scores (lane n and n+64); rotation swizzle kills bank conflicts
    float a0 = 0.f, a1 = 0.f;
#pragma unroll 8
    for (int d0 = 0; d0 < 64; d0++) {
      const int dd = (d0 + lane) & 63;
      const float qq = qb[w][dd];
      a0 += qq * kc_s[lane * 64 + dd];
      a1 += qq * kc_s[(lane + 64) * 64 + dd];
    }
    const float s0 = (lane < count) ? a0 * 0.125f : NEGC;
    const float s1 = (lane + 64 < count) ? a1 * 0.125f : NEGC;
    const float M = wred_max(fmaxf(s0, s1));
    const float e0 = __expf(s0 - M), e1 = __expf(s1 - M);
    const float inv = 1.f / wred_sum(e0 + e1);
    pb[w][lane] = e0 * inv;
    pb[w][lane + 64] = e1 * inv;

    float oc = 0.f;  // count==0 -> stays 0 (matches nan_to_num/any-mask)
#pragma unroll 4
    for (int n = 0; n < count; n++)
      oc += pb[w][n] * __bfloat162float(vc_s[n * 64 + lane]);

    // ---- top-4 selection, tie-break lower index (matches jax.lax.top_k)
    float c0 = s0, c1 = s1;
    int sel0 = 0, sel1 = 0, sel2 = 0, sel3 = 0;
#pragma unroll
    for (int j = 0; j < 4; j++) {
      float bv; int bi;
      if (c0 >= c1) { bv = c0; bi = lane; } else { bv = c1; bi = lane + 64; }
#pragma unroll
      for (int o = 32; o > 0; o >>= 1) {
        const float ov = __shfl_xor(bv, o, 64);
        const int oi = __shfl_xor(bi, o, 64);
        if (ov > bv || (ov == bv && oi < bi)) { bv = ov; bi = oi; }
      }
      if (j == 0) sel0 = bi; else if (j == 1) sel1 = bi;
      else if (j == 2) sel2 = bi; else sel3 = bi;
      if (bi == lane) c0 = -FLT_MAX;
      if (bi == lane + 64) c1 = -FLT_MAX;
    }

    // ---- selected branch: 4 blocks x 16 tokens, one token per lane
    const int g16 = lane >> 4;
    const int blk = (g16 == 0) ? sel0 : (g16 == 1) ? sel1 : (g16 == 2) ? sel2 : sel3;
    const int tok = blk * 16 + (lane & 15);
    float as_ = 0.f;
#pragma unroll 8
    for (int d = 0; d < 64; d++)
      as_ += qb[w][d] * kTh[(size_t)d * T_LEN + tok];
    const float sv_ = (tok <= t) ? as_ * 0.125f : NEGC;
    const float Ms = wred_max(sv_);
    const float es = __expf(sv_ - Ms);
    ps[w][lane] = es * (1.f / wred_sum(es));

    float os = 0.f;
#pragma unroll
    for (int jb = 0; jb < 4; jb++) {
      const int b2 = (jb == 0) ? sel0 : (jb == 1) ? sel1 : (jb == 2) ? sel2 : sel3;
#pragma unroll 4
      for (int l2 = 0; l2 < 16; l2++)
        os += ps[w][jb * 16 + l2] * vh[(size_t)(b2 * 16 + l2) * DM + lane];
    }

    // ---- sliding-window branch: tokens t-32..t, one per lane (lanes 33..63 idle)
    const int tw = t - 32 + lane;
    const int twc = min(max(tw, 0), T_LEN - 1);
    float aw = 0.f;
#pragma unroll 8
    for (int d = 0; d < 64; d++)
      aw += qb[w][d] * kTh[(size_t)d * T_LEN + twc];
    const float swv = (tw >= 0 && lane <= 32) ? aw * 0.125f : NEGC;
    const float Mw = wred_max(swv);
    const float ew = __expf(swv - Mw);
    pw[w][lane] = ew * (1.f / wred_sum(ew));

    float ol = 0.f;
#pragma unroll 4
    for (int l = 0; l <= 32; l++) {
      const int tk = max(t - 32 + l, 0);
      ol += pw[w][l] * vh[(size_t)tk * DM + lane];
    }

    const float g0 = gates[t * 3 + 0], g1 = gates[t * 3 + 1], g2 = gates[t * 3 + 2];
    outf[(size_t)t * DM + h * 64 + lane] = g0 * oc + g1 * os + g2 * ol;
  }
}

// ---------------- launch ----------------
extern "C" void kernel_launch(void* const* d_in, const int* in_sizes, int n_in,
                              void* d_out, int out_size, void* d_ws, size_t ws_size,
                              hipStream_t stream) {
  const float* x   = (const float*)d_in[0];
  const float* Wq  = (const float*)d_in[1];
  const float* Wk  = (const float*)d_in[2];
  const float* Wv  = (const float*)d_in[3];
  const float* Wo  = (const float*)d_in[4];
  const float* Wck = (const float*)d_in[5];
  const float* Wcv = (const float*)d_in[6];
  const float* Wg  = (const float*)d_in[7];
  const float* bg  = (const float*)d_in[8];
  float* out = (float*)d_out;

  float* ws = (float*)d_ws;
  const size_t SZ = (size_t)T_LEN * DM;  // 2M floats
  float* q     = ws;
  float* k     = ws + SZ;
  float* v     = ws + 2 * SZ;
  float* kT    = ws + 3 * SZ;
  float* outf  = ws + 4 * SZ;
  float* kc    = ws + 5 * SZ;            // 16*128*64 = 131072
  float* vc    = kc + 131072;
  float* gates = vc + 131072;            // 2048*3

  dim3 gemm_grid(DM / 64, T_LEN / 64);
  gemm_f32<<<gemm_grid, 256, 0, stream>>>(x, Wq, q, T_LEN, DM, DM);
  gemm_f32<<<gemm_grid, 256, 0, stream>>>(x, Wk, k, T_LEN, DM, DM);
  gemm_f32<<<gemm_grid, 256, 0, stream>>>(x, Wv, v, T_LEN, DM, DM);

  transpose_k<<<dim3(DM / 32, T_LEN / 32), dim3(32, 8), 0, stream>>>(k, kT);
  compress_kv<<<dim3(NB / 8, 16), 256, 0, stream>>>(k, v, Wck, Wcv, kc, vc);
  gates_k<<<T_LEN / 4, 256, 0, stream>>>(q, Wg, bg, gates);

  nsa_attn<<<dim3(T_LEN / 32, 16), 256, 0, stream>>>(q, kT, v, kc, vc, gates, outf);

  gemm_f32<<<gemm_grid, 256, 0, stream>>>(outf, Wo, out, T_LEN, DM, DM);
}

// Round 2
// 862.652 us; speedup vs baseline: 1.0512x; 1.0512x over previous
//
#include <hip/hip_runtime.h>
#include <hip/hip_bf16.h>
#include <float.h>

#define T_LEN 2048
#define DM    1024
#define NB    128
#define NEGC  (-1e9f)

typedef __attribute__((ext_vector_type(8))) short short8;
typedef __attribute__((ext_vector_type(4))) float floatx4;

// ---------------- helpers ----------------
__device__ __forceinline__ float wred_max(float v) {
#pragma unroll
  for (int o = 32; o > 0; o >>= 1) v = fmaxf(v, __shfl_xor(v, o, 64));
  return v;
}
__device__ __forceinline__ float wred_sum(float v) {
#pragma unroll
  for (int o = 32; o > 0; o >>= 1) v += __shfl_xor(v, o, 64);
  return v;
}
__device__ __forceinline__ unsigned short f32_to_bf16(float f) {
  unsigned int b = __float_as_uint(f);
  return (unsigned short)((b + 0x7fffu + ((b >> 16) & 1u)) >> 16);
}
__device__ __forceinline__ float bf16_to_f32(unsigned short u) {
  return __uint_as_float(((unsigned int)u) << 16);
}
__device__ __forceinline__ float bf_lo(unsigned int u) { return __uint_as_float(u << 16); }
__device__ __forceinline__ float bf_hi(unsigned int u) { return __uint_as_float(u & 0xffff0000u); }

__device__ __forceinline__ void lds_async16(unsigned short* l, const unsigned short* g) {
  __builtin_amdgcn_global_load_lds(
      (const __attribute__((address_space(1))) unsigned int*)g,
      (__attribute__((address_space(3))) unsigned int*)l, 16, 0, 0);
}

// ---------------- bf16 MFMA GEMM: C(M,N) f32 = A(M,K)bf16 @ Bt(N,K)bf16^T ----
// 128x128 tile, BK=32, 256 threads (4 waves in 2x2), 4x4 mfma_f32_16x16x32_bf16.
__global__ __launch_bounds__(256) void gemm_bt(const unsigned short* __restrict__ A,
                                               const unsigned short* __restrict__ Bt,
                                               float* __restrict__ C,
                                               int M, int N, int K) {
  __shared__ __align__(16) unsigned short As[128 * 32];
  __shared__ __align__(16) unsigned short Bs[128 * 32];
  const int tid = threadIdx.x;
  const int w = tid >> 6, lane = tid & 63;
  const int row0 = blockIdx.y * 128, col0 = blockIdx.x * 128;
  const int wr = w >> 1, wc = w & 1;

  const int r1 = tid >> 2, p1 = tid & 3;           // chunk tid
  const int r2 = r1 + 64, p2 = p1;                 // chunk tid+256

  floatx4 zero = {0.f, 0.f, 0.f, 0.f};
  floatx4 acc[4][4];
#pragma unroll
  for (int i = 0; i < 4; i++)
#pragma unroll
    for (int j = 0; j < 4; j++) acc[i][j] = zero;

  for (int k0 = 0; k0 < K; k0 += 32) {
    lds_async16(&As[w * 512],        A + (size_t)(row0 + r1) * K + k0 + p1 * 8);
    lds_async16(&As[w * 512 + 2048], A + (size_t)(row0 + r2) * K + k0 + p2 * 8);
    lds_async16(&Bs[w * 512],        Bt + (size_t)(col0 + r1) * K + k0 + p1 * 8);
    lds_async16(&Bs[w * 512 + 2048], Bt + (size_t)(col0 + r2) * K + k0 + p2 * 8);
    __syncthreads();
    short8 af[4], bf[4];
#pragma unroll
    for (int mi = 0; mi < 4; mi++)
      af[mi] = *(const short8*)&As[(wr * 64 + mi * 16 + (lane & 15)) * 32 + (lane >> 4) * 8];
#pragma unroll
    for (int ni = 0; ni < 4; ni++)
      bf[ni] = *(const short8*)&Bs[(wc * 64 + ni * 16 + (lane & 15)) * 32 + (lane >> 4) * 8];
#pragma unroll
    for (int mi = 0; mi < 4; mi++)
#pragma unroll
      for (int ni = 0; ni < 4; ni++)
        acc[mi][ni] = __builtin_amdgcn_mfma_f32_16x16x32_bf16(af[mi], bf[ni], acc[mi][ni], 0, 0, 0);
    __syncthreads();
  }
  const int ccol = lane & 15, crow4 = (lane >> 4) * 4;
#pragma unroll
  for (int mi = 0; mi < 4; mi++)
#pragma unroll
    for (int ni = 0; ni < 4; ni++) {
      float* Cp = C + (size_t)(row0 + wr * 64 + mi * 16 + crow4) * N + col0 + wc * 64 + ni * 16 + ccol;
      Cp[0] = acc[mi][ni][0];
      Cp[(size_t)N] = acc[mi][ni][1];
      Cp[(size_t)2 * N] = acc[mi][ni][2];
      Cp[(size_t)3 * N] = acc[mi][ni][3];
    }
}

// ---------------- cast x -> A'' = [x_hi | x_lo | x_hi] (2048 x 3072 bf16) ----
__global__ __launch_bounds__(256) void cast_x_k(const float* __restrict__ x,
                                                unsigned short* __restrict__ Axx) {
  const int gid = blockIdx.x * 256 + threadIdx.x;  // 0..524287 (float4 units)
  float4 xv = ((const float4*)x)[gid];
  const int m = gid >> 8;        // 256 float4 per 1024-row
  const int c = (gid & 255) * 4;
  float vv[4] = {xv.x, xv.y, xv.z, xv.w};
  unsigned short h[4], l[4];
#pragma unroll
  for (int j = 0; j < 4; j++) {
    h[j] = f32_to_bf16(vv[j]);
    l[j] = f32_to_bf16(vv[j] - bf16_to_f32(h[j]));
  }
  ushort4 hv = make_ushort4(h[0], h[1], h[2], h[3]);
  ushort4 lv = make_ushort4(l[0], l[1], l[2], l[3]);
  *(ushort4*)&Axx[(size_t)m * 3072 + c] = hv;
  *(ushort4*)&Axx[(size_t)m * 3072 + 1024 + c] = lv;
  *(ushort4*)&Axx[(size_t)m * 3072 + 2048 + c] = hv;
}

// ---- transpose-cast W(1024x1024)[k][n] -> Bt rows n0..n0+1023: hi@k, hi@k+1024, lo@k+2048
__global__ void cast_wt3(const float* __restrict__ W, unsigned short* __restrict__ Bt, int n0) {
  __shared__ float tile[32][33];
  const int kt0 = blockIdx.y * 32, nt0 = blockIdx.x * 32;
  const int tx = threadIdx.x, ty = threadIdx.y;
#pragma unroll
  for (int i = 0; i < 32; i += 8)
    tile[ty + i][tx] = W[(size_t)(kt0 + ty + i) * 1024 + nt0 + tx];
  __syncthreads();
#pragma unroll
  for (int i = 0; i < 32; i += 8) {
    const int n = nt0 + ty + i, kk = kt0 + tx;
    const float f = tile[tx][ty + i];
    const unsigned short hb = f32_to_bf16(f);
    const unsigned short lb = f32_to_bf16(f - bf16_to_f32(hb));
    const size_t base = (size_t)(n0 + n) * 3072;
    Bt[base + kk] = hb;
    Bt[base + 1024 + kk] = hb;
    Bt[base + 2048 + kk] = lb;
  }
}

// ---- transpose-cast Wo(1024x1024) -> Wot (1024 n x 1024 k) bf16, single hi ----
__global__ void cast_wt1(const float* __restrict__ W, unsigned short* __restrict__ Bt) {
  __shared__ float tile[32][33];
  const int kt0 = blockIdx.y * 32, nt0 = blockIdx.x * 32;
  const int tx = threadIdx.x, ty = threadIdx.y;
#pragma unroll
  for (int i = 0; i < 32; i += 8)
    tile[ty + i][tx] = W[(size_t)(kt0 + ty + i) * 1024 + nt0 + tx];
  __syncthreads();
#pragma unroll
  for (int i = 0; i < 32; i += 8) {
    const int n = nt0 + ty + i, kk = kt0 + tx;
    Bt[(size_t)n * 1024 + kk] = f32_to_bf16(tile[tx][ty + i]);
  }
}

// ---------------- reorg: C qkv cols -> kh, vh as (H, T, D) f32 ----------------
__global__ __launch_bounds__(256) void reorg_kv(const float* __restrict__ C,
                                                float* __restrict__ kh,
                                                float* __restrict__ vh) {
  const int o = blockIdx.x * 256 + threadIdx.x;   // float4 units, 0..1048575
  const int d4 = o & 15;
  const int t = (o >> 4) & 2047;
  const int hh = o >> 15;          // 0..31
  const int h = hh & 15, sel = hh >> 4;
  float4 val = *(const float4*)&C[(size_t)t * 3072 + 1024 + sel * 1024 + h * 64 + d4 * 4];
  float* dst = sel ? vh : kh;
  *(float4*)&dst[((size_t)h * 2048 + t) * 64 + d4 * 4] = val;
}

// ---------------- compressed K/V from kh/vh (H,T,D) ----------------
__global__ __launch_bounds__(256) void compress_kv(
    const float* __restrict__ kh, const float* __restrict__ vh,
    const float* __restrict__ Wck, const float* __restrict__ Wcv,
    float* __restrict__ kc, float* __restrict__ vc) {
  __shared__ float sb[4][2][1024];
  const int h = blockIdx.y;
  const int w = threadIdx.x >> 6, lane = threadIdx.x & 63;
  const int n0 = blockIdx.x * 8 + w * 2;

#pragma unroll
  for (int m = 0; m < 2; m++)
#pragma unroll 4
    for (int i = 0; i < 16; i++)
      sb[w][m][i * 64 + lane] = kh[((size_t)h * 2048 + (n0 + m) * 16 + i) * 64 + lane];
  float a0 = 0.f, a1 = 0.f;
#pragma unroll 4
  for (int i = 0; i < 1024; i++) {
    float wk = Wck[i * 64 + lane];
    a0 += sb[w][0][i] * wk;
    a1 += sb[w][1][i] * wk;
  }
  kc[h * 8192 + n0 * 64 + lane] = a0;
  kc[h * 8192 + (n0 + 1) * 64 + lane] = a1;

#pragma unroll
  for (int m = 0; m < 2; m++)
#pragma unroll 4
    for (int i = 0; i < 16; i++)
      sb[w][m][i * 64 + lane] = vh[((size_t)h * 2048 + (n0 + m) * 16 + i) * 64 + lane];
  a0 = 0.f; a1 = 0.f;
#pragma unroll 4
  for (int i = 0; i < 1024; i++) {
    float wv = Wcv[i * 64 + lane];
    a0 += sb[w][0][i] * wv;
    a1 += sb[w][1][i] * wv;
  }
  vc[h * 8192 + n0 * 64 + lane] = a0;
  vc[h * 8192 + (n0 + 1) * 64 + lane] = a1;
}

// ---------------- gates ----------------
__global__ __launch_bounds__(256) void gates_k(const float* __restrict__ C,
                                               const float* __restrict__ Wg,
                                               const float* __restrict__ bg,
                                               float* __restrict__ gates) {
  const int w = threadIdx.x >> 6, lane = threadIdx.x & 63;
  const int t = blockIdx.x * 4 + w;
  float m = 0.f;
#pragma unroll
  for (int h = 0; h < 16; h++) m += C[(size_t)t * 3072 + h * 64 + lane];
  m *= (1.f / 16.f);
  float g0 = wred_sum(m * Wg[lane * 3 + 0]);
  float g1 = wred_sum(m * Wg[lane * 3 + 1]);
  float g2 = wred_sum(m * Wg[lane * 3 + 2]);
  if (lane == 0) {
    g0 += bg[0]; g1 += bg[1]; g2 += bg[2];
    float mx = fmaxf(g0, fmaxf(g1, g2));
    float e0 = __expf(g0 - mx), e1 = __expf(g1 - mx), e2 = __expf(g2 - mx);
    float inv = 1.f / (e0 + e1 + e2);
    gates[t * 3 + 0] = e0 * inv;
    gates[t * 3 + 1] = e1 * inv;
    gates[t * 3 + 2] = e2 * inv;
  }
}

// ---------------- fused NSA attention ----------------
// 1D grid 1024 blocks; XCD-partitioned: 2 heads per XCD for L2 locality.
__global__ __launch_bounds__(256) void nsa_attn(
    const float* __restrict__ C, const float* __restrict__ kh,
    const float* __restrict__ vh, const float* __restrict__ kc,
    const float* __restrict__ vc, const float* __restrict__ gates,
    unsigned short* __restrict__ outf) {
  __shared__ __align__(16) float kc_s[NB * 64];           // rotated rows, 32KB
  __shared__ __align__(16) unsigned short vc_s[64 * 136]; // [d][n] bf16, pitch 136
  __shared__ __align__(16) float qb[4][64];
  __shared__ __align__(16) float pb[4][128];
  __shared__ __align__(16) float psw[4][64];              // selected softmax, then window

  const int id = blockIdx.x;
  const int xcd = id & 7, slot = id >> 3;
  const int h = xcd * 2 + (slot & 1);
  const int t0 = (slot >> 1) * 32;
  const int tid = threadIdx.x;
  const int w = tid >> 6;
  const int lane = tid & 63;

  // stage kc (rotated fp32) and vc (transposed bf16)
  for (int it = 0; it < 32; it++) {
    const int idx = it * 256 + tid;
    const int n = idx >> 6, d = idx & 63;
    kc_s[n * 64 + ((d + 4 * n) & 63)] = kc[h * 8192 + idx];
    vc_s[d * 136 + n] = f32_to_bf16(vc[h * 8192 + idx]);
  }
  __syncthreads();

  const float* khh = kh + (size_t)h * 2048 * 64;
  const float* vhh = vh + (size_t)h * 2048 * 64;
  const float4* qb4 = (const float4*)qb[w];
  const float4* pb4 = (const float4*)pb[w];
  const uint4* vrow = (const uint4*)&vc_s[lane * 136];

  for (int i = 0; i < 8; i++) {
    const int t = t0 + w * 8 + i;
    const int count = t >> 4;
    qb[w][lane] = C[(size_t)t * 3072 + h * 64 + lane];

    // ---- compressed scores: rows lane, lane+64 via rotated b128 reads
    float a0 = 0.f, a1 = 0.f;
#pragma unroll
    for (int j = 0; j < 16; j++) {
      const int g = ((j + lane) & 15) * 4;
      const float4 qv = qb4[j];
      const float4 k0v = *(const float4*)&kc_s[lane * 64 + g];
      const float4 k1v = *(const float4*)&kc_s[(lane + 64) * 64 + g];
      a0 += qv.x * k0v.x + qv.y * k0v.y + qv.z * k0v.z + qv.w * k0v.w;
      a1 += qv.x * k1v.x + qv.y * k1v.y + qv.z * k1v.z + qv.w * k1v.w;
    }
    const float s0 = (lane < count) ? a0 * 0.125f : NEGC;
    const float s1 = (lane + 64 < count) ? a1 * 0.125f : NEGC;
    const float M = wred_max(fmaxf(s0, s1));
    const float e0 = __expf(s0 - M), e1 = __expf(s1 - M);
    const float inv = 1.f / wred_sum(e0 + e1);
    pb[w][lane] = e0 * inv;
    pb[w][lane + 64] = e1 * inv;

    // ---- out_c: lane = d, b128 over transposed bf16 vc (masked entries have p=0)
    float oc = 0.f;
#pragma unroll
    for (int cc = 0; cc < 16; cc++) {
      const uint4 raw = vrow[cc];
      const float4 pA = pb4[cc * 2], pB = pb4[cc * 2 + 1];
      oc += pA.x * bf_lo(raw.x) + pA.y * bf_hi(raw.x)
          + pA.z * bf_lo(raw.y) + pA.w * bf_hi(raw.y)
          + pB.x * bf_lo(raw.z) + pB.y * bf_hi(raw.z)
          + pB.z * bf_lo(raw.w) + pB.w * bf_hi(raw.w);
    }
    if (count == 0) oc = 0.f;  // softmax over all-NEG is uniform; ref zeroes it

    // ---- top-4, tie-break lower index (jax.lax.top_k semantics)
    float c0 = s0, c1 = s1;
    int sel0 = 0, sel1 = 0, sel2 = 0, sel3 = 0;
#pragma unroll
    for (int j = 0; j < 4; j++) {
      float bv; int bi;
      if (c0 >= c1) { bv = c0; bi = lane; } else { bv = c1; bi = lane + 64; }
#pragma unroll
      for (int o = 32; o > 0; o >>= 1) {
        const float ov = __shfl_xor(bv, o, 64);
        const int oi = __shfl_xor(bi, o, 64);
        if (ov > bv || (ov == bv && oi < bi)) { bv = ov; bi = oi; }
      }
      if (j == 0) sel0 = bi; else if (j == 1) sel1 = bi;
      else if (j == 2) sel2 = bi; else sel3 = bi;
      if (bi == lane) c0 = -FLT_MAX;
      if (bi == lane + 64) c1 = -FLT_MAX;
    }

    // ---- selected branch: one gathered token per lane, row-major k gather
    const int g16 = lane >> 4;
    const int blk = (g16 == 0) ? sel0 : (g16 == 1) ? sel1 : (g16 == 2) ? sel2 : sel3;
    const int tok = blk * 16 + (lane & 15);
    const float* krow = khh + (size_t)tok * 64;
    float as_ = 0.f;
#pragma unroll
    for (int j = 0; j < 16; j++) {
      const float4 kj = *(const float4*)&krow[j * 4];
      const float4 qj = qb4[j];
      as_ += qj.x * kj.x + qj.y * kj.y + qj.z * kj.z + qj.w * kj.w;
    }
    const float sv_ = (tok <= t) ? as_ * 0.125f : NEGC;
    const float Ms = wred_max(sv_);
    const float es = __expf(sv_ - Ms);
    psw[w][lane] = es * (1.f / wred_sum(es));

    float os = 0.f;
#pragma unroll
    for (int jb = 0; jb < 4; jb++) {
      const int b2 = (jb == 0) ? sel0 : (jb == 1) ? sel1 : (jb == 2) ? sel2 : sel3;
#pragma unroll 4
      for (int l2 = 0; l2 < 16; l2++)
        os += psw[w][jb * 16 + l2] * vhh[(size_t)(b2 * 16 + l2) * 64 + lane];
    }

    // ---- sliding window: keys t-32..t, one per lane (lanes 33..63 masked)
    const int tw = t - 32 + lane;
    const int twc = min(max(tw, 0), T_LEN - 1);
    const float* kwrow = khh + (size_t)twc * 64;
    float aw = 0.f;
#pragma unroll
    for (int j = 0; j < 16; j++) {
      const float4 kj = *(const float4*)&kwrow[j * 4];
      const float4 qj = qb4[j];
      aw += qj.x * kj.x + qj.y * kj.y + qj.z * kj.z + qj.w * kj.w;
    }
    const float swv = (tw >= 0 && lane <= 32) ? aw * 0.125f : NEGC;
    const float Mw = wred_max(swv);
    const float ew = __expf(swv - Mw);
    psw[w][lane] = ew * (1.f / wred_sum(ew));  // reuse buffer (same wave, in-order LDS)

    float ol = 0.f;
#pragma unroll 4
    for (int l = 0; l <= 32; l++) {
      const int tk = max(t - 32 + l, 0);
      ol += psw[w][l] * vhh[(size_t)tk * 64 + lane];
    }

    const float g0 = gates[t * 3 + 0], g1 = gates[t * 3 + 1], g2 = gates[t * 3 + 2];
    outf[(size_t)t * DM + h * 64 + lane] = f32_to_bf16(g0 * oc + g1 * os + g2 * ol);
  }
}

// ---------------- launch ----------------
extern "C" void kernel_launch(void* const* d_in, const int* in_sizes, int n_in,
                              void* d_out, int out_size, void* d_ws, size_t ws_size,
                              hipStream_t stream) {
  const float* x   = (const float*)d_in[0];
  const float* Wq  = (const float*)d_in[1];
  const float* Wk  = (const float*)d_in[2];
  const float* Wv  = (const float*)d_in[3];
  const float* Wo  = (const float*)d_in[4];
  const float* Wck = (const float*)d_in[5];
  const float* Wcv = (const float*)d_in[6];
  const float* Wg  = (const float*)d_in[7];
  const float* bg  = (const float*)d_in[8];
  float* out = (float*)d_out;

  float* ws = (float*)d_ws;
  // persistent: C (2048x3072 f32)
  float* C = ws;                                   // 6,291,456 floats
  // phase-1 overlay (dead after qkv GEMM):
  unsigned short* Axx  = (unsigned short*)(ws + 6291456);   // 2048x3072 bf16
  unsigned short* Bqkv = (unsigned short*)(ws + 6291456 + 3145728);  // 3072x3072 bf16
  // phase-2 overlay (same region, written after qkv GEMM):
  float* kh = ws + 6291456;                        // 16x2048x64
  float* vh = ws + 8388608;
  unsigned short* outf = (unsigned short*)(ws + 10485760);  // 2048x1024 bf16
  unsigned short* Wot  = (unsigned short*)(ws + 11534336);  // 1024x1024 bf16
  float* kc    = ws + 12058624;                    // 16x128x64
  float* vc    = ws + 12189696;
  float* gates = ws + 12320768;                    // 2048x3

  // 1. build A'' and B'' (bf16x3 split for fp32-accurate q/k selection path)
  cast_x_k<<<2048, 256, 0, stream>>>(x, Axx);
  cast_wt3<<<dim3(32, 32), dim3(32, 8), 0, stream>>>(Wq, Bqkv, 0);
  cast_wt3<<<dim3(32, 32), dim3(32, 8), 0, stream>>>(Wk, Bqkv, 1024);
  cast_wt3<<<dim3(32, 32), dim3(32, 8), 0, stream>>>(Wv, Bqkv, 2048);

  // 2. fused qkv GEMM: C = A''(2048x3072) @ B''^T -> [q | k | v] fp32
  gemm_bt<<<dim3(24, 16), 256, 0, stream>>>(Axx, Bqkv, C, 2048, 3072, 3072);

  // 3. reorganize k,v to (H,T,D); compress; gates; cast Wo
  reorg_kv<<<4096, 256, 0, stream>>>(C, kh, vh);
  compress_kv<<<dim3(16, 16), 256, 0, stream>>>(kh, vh, Wck, Wcv, kc, vc);
  gates_k<<<512, 256, 0, stream>>>(C, Wg, bg, gates);
  cast_wt1<<<dim3(32, 32), dim3(32, 8), 0, stream>>>(Wo, Wot);

  // 4. fused attention (writes bf16 outf)
  nsa_attn<<<1024, 256, 0, stream>>>(C, kh, vh, kc, vc, gates, outf);

  // 5. output projection: out = outf @ Wo (bf16 MFMA)
  gemm_bt<<<dim3(8, 16), 256, 0, stream>>>(outf, Wot, out, 2048, 1024, 1024);
}

// Round 3
// 594.653 us; speedup vs baseline: 1.5249x; 1.4507x over previous
//
#include <hip/hip_runtime.h>
#include <hip/hip_bf16.h>
#include <float.h>

#define T_LEN 2048
#define DM    1024
#define NB    128
#define NEGC  (-1e9f)

typedef __attribute__((ext_vector_type(8))) short short8;
typedef __attribute__((ext_vector_type(4))) float floatx4;

// ---------------- helpers ----------------
__device__ __forceinline__ float wred_max(float v) {
#pragma unroll
  for (int o = 32; o > 0; o >>= 1) v = fmaxf(v, __shfl_xor(v, o, 64));
  return v;
}
__device__ __forceinline__ float wred_sum(float v) {
#pragma unroll
  for (int o = 32; o > 0; o >>= 1) v += __shfl_xor(v, o, 64);
  return v;
}
__device__ __forceinline__ unsigned short f32_to_bf16(float f) {
  unsigned int b = __float_as_uint(f);
  return (unsigned short)((b + 0x7fffu + ((b >> 16) & 1u)) >> 16);
}
__device__ __forceinline__ float bf16_to_f32(unsigned short u) {
  return __uint_as_float(((unsigned int)u) << 16);
}
__device__ __forceinline__ void lds_async16(unsigned short* l, const unsigned short* g) {
  __builtin_amdgcn_global_load_lds(
      (const __attribute__((address_space(1))) unsigned int*)g,
      (__attribute__((address_space(3))) unsigned int*)l, 16, 0, 0);
}

// ---------------- bf16 MFMA GEMM: C(M,N) f32 = A(M,K)bf16 @ Bt(N,K)bf16^T ----
__global__ __launch_bounds__(256) void gemm_bt(const unsigned short* __restrict__ A,
                                               const unsigned short* __restrict__ Bt,
                                               float* __restrict__ C,
                                               int M, int N, int K) {
  __shared__ __align__(16) unsigned short As[128 * 32];
  __shared__ __align__(16) unsigned short Bs[128 * 32];
  const int tid = threadIdx.x;
  const int w = tid >> 6, lane = tid & 63;
  const int row0 = blockIdx.y * 128, col0 = blockIdx.x * 128;
  const int wr = w >> 1, wc = w & 1;
  const int r1 = tid >> 2, p1 = tid & 3;
  const int r2 = r1 + 64;

  floatx4 zero = {0.f, 0.f, 0.f, 0.f};
  floatx4 acc[4][4];
#pragma unroll
  for (int i = 0; i < 4; i++)
#pragma unroll
    for (int j = 0; j < 4; j++) acc[i][j] = zero;

  for (int k0 = 0; k0 < K; k0 += 32) {
    lds_async16(&As[w * 512],        A + (size_t)(row0 + r1) * K + k0 + p1 * 8);
    lds_async16(&As[w * 512 + 2048], A + (size_t)(row0 + r2) * K + k0 + p1 * 8);
    lds_async16(&Bs[w * 512],        Bt + (size_t)(col0 + r1) * K + k0 + p1 * 8);
    lds_async16(&Bs[w * 512 + 2048], Bt + (size_t)(col0 + r2) * K + k0 + p1 * 8);
    __syncthreads();
    short8 af[4], bf[4];
#pragma unroll
    for (int mi = 0; mi < 4; mi++)
      af[mi] = *(const short8*)&As[(wr * 64 + mi * 16 + (lane & 15)) * 32 + (lane >> 4) * 8];
#pragma unroll
    for (int ni = 0; ni < 4; ni++)
      bf[ni] = *(const short8*)&Bs[(wc * 64 + ni * 16 + (lane & 15)) * 32 + (lane >> 4) * 8];
#pragma unroll
    for (int mi = 0; mi < 4; mi++)
#pragma unroll
      for (int ni = 0; ni < 4; ni++)
        acc[mi][ni] = __builtin_amdgcn_mfma_f32_16x16x32_bf16(af[mi], bf[ni], acc[mi][ni], 0, 0, 0);
    __syncthreads();
  }
  const int ccol = lane & 15, crow4 = (lane >> 4) * 4;
#pragma unroll
  for (int mi = 0; mi < 4; mi++)
#pragma unroll
    for (int ni = 0; ni < 4; ni++) {
      float* Cp = C + (size_t)(row0 + wr * 64 + mi * 16 + crow4) * N + col0 + wc * 64 + ni * 16 + ccol;
      Cp[0] = acc[mi][ni][0];
      Cp[(size_t)N] = acc[mi][ni][1];
      Cp[(size_t)2 * N] = acc[mi][ni][2];
      Cp[(size_t)3 * N] = acc[mi][ni][3];
    }
}

// ---------------- cast x -> A'' = [x_hi | x_lo | x_hi] ----------------
__global__ __launch_bounds__(256) void cast_x_k(const float* __restrict__ x,
                                                unsigned short* __restrict__ Axx) {
  const int gid = blockIdx.x * 256 + threadIdx.x;
  float4 xv = ((const float4*)x)[gid];
  const int m = gid >> 8;
  const int c = (gid & 255) * 4;
  float vv[4] = {xv.x, xv.y, xv.z, xv.w};
  unsigned short h[4], l[4];
#pragma unroll
  for (int j = 0; j < 4; j++) {
    h[j] = f32_to_bf16(vv[j]);
    l[j] = f32_to_bf16(vv[j] - bf16_to_f32(h[j]));
  }
  ushort4 hv = make_ushort4(h[0], h[1], h[2], h[3]);
  ushort4 lv = make_ushort4(l[0], l[1], l[2], l[3]);
  *(ushort4*)&Axx[(size_t)m * 3072 + c] = hv;
  *(ushort4*)&Axx[(size_t)m * 3072 + 1024 + c] = lv;
  *(ushort4*)&Axx[(size_t)m * 3072 + 2048 + c] = hv;
}

__global__ void cast_wt3(const float* __restrict__ W, unsigned short* __restrict__ Bt, int n0) {
  __shared__ float tile[32][33];
  const int kt0 = blockIdx.y * 32, nt0 = blockIdx.x * 32;
  const int tx = threadIdx.x, ty = threadIdx.y;
#pragma unroll
  for (int i = 0; i < 32; i += 8)
    tile[ty + i][tx] = W[(size_t)(kt0 + ty + i) * 1024 + nt0 + tx];
  __syncthreads();
#pragma unroll
  for (int i = 0; i < 32; i += 8) {
    const int n = nt0 + ty + i, kk = kt0 + tx;
    const float f = tile[tx][ty + i];
    const unsigned short hb = f32_to_bf16(f);
    const unsigned short lb = f32_to_bf16(f - bf16_to_f32(hb));
    const size_t base = (size_t)(n0 + n) * 3072;
    Bt[base + kk] = hb;
    Bt[base + 1024 + kk] = hb;
    Bt[base + 2048 + kk] = lb;
  }
}

__global__ void cast_wt1(const float* __restrict__ W, unsigned short* __restrict__ Bt) {
  __shared__ float tile[32][33];
  const int kt0 = blockIdx.y * 32, nt0 = blockIdx.x * 32;
  const int tx = threadIdx.x, ty = threadIdx.y;
#pragma unroll
  for (int i = 0; i < 32; i += 8)
    tile[ty + i][tx] = W[(size_t)(kt0 + ty + i) * 1024 + nt0 + tx];
  __syncthreads();
#pragma unroll
  for (int i = 0; i < 32; i += 8) {
    const int n = nt0 + ty + i, kk = kt0 + tx;
    Bt[(size_t)n * 1024 + kk] = f32_to_bf16(tile[tx][ty + i]);
  }
}

// ---------------- reorg: C(t,3072) -> qh (T,1024), kh/vh (H,T,64) ----------------
__global__ __launch_bounds__(256) void reorg_qkv(const float* __restrict__ C,
                                                 float* __restrict__ qh,
                                                 float* __restrict__ kh,
                                                 float* __restrict__ vh) {
  const int gid = blockIdx.x * 256 + threadIdx.x;  // float4 units, 0..1572863
  const int t = gid / 768;
  const int c = (gid - t * 768) * 4;
  float4 val = *(const float4*)&C[(size_t)t * 3072 + c];
  if (c < 1024) {
    *(float4*)&qh[(size_t)t * 1024 + c] = val;
  } else {
    const int h = (c >> 6) & 15, d = c & 63;
    float* dst = (c < 2048) ? kh : vh;
    *(float4*)&dst[((size_t)h * 2048 + t) * 64 + d] = val;
  }
}

// ---------------- compressed K/V -> kc_hi/kc_lo bf16 (H,NB,64), vcT bf16 (H,64,NB)
__global__ __launch_bounds__(256) void compress_kv(
    const float* __restrict__ kh, const float* __restrict__ vh,
    const float* __restrict__ Wck, const float* __restrict__ Wcv,
    unsigned short* __restrict__ kc_hi, unsigned short* __restrict__ kc_lo,
    unsigned short* __restrict__ vcT) {
  __shared__ float sb[4][2][1024];
  const int h = blockIdx.y;
  const int w = threadIdx.x >> 6, lane = threadIdx.x & 63;
  const int n0 = blockIdx.x * 8 + w * 2;

#pragma unroll
  for (int m = 0; m < 2; m++)
#pragma unroll 4
    for (int i = 0; i < 16; i++)
      sb[w][m][i * 64 + lane] = kh[((size_t)h * 2048 + (n0 + m) * 16 + i) * 64 + lane];
  float a0 = 0.f, a1 = 0.f;
#pragma unroll 4
  for (int i = 0; i < 1024; i++) {
    float wk = Wck[i * 64 + lane];
    a0 += sb[w][0][i] * wk;
    a1 += sb[w][1][i] * wk;
  }
  {
    unsigned short h0 = f32_to_bf16(a0), h1 = f32_to_bf16(a1);
    kc_hi[h * 8192 + n0 * 64 + lane] = h0;
    kc_hi[h * 8192 + (n0 + 1) * 64 + lane] = h1;
    kc_lo[h * 8192 + n0 * 64 + lane] = f32_to_bf16(a0 - bf16_to_f32(h0));
    kc_lo[h * 8192 + (n0 + 1) * 64 + lane] = f32_to_bf16(a1 - bf16_to_f32(h1));
  }

#pragma unroll
  for (int m = 0; m < 2; m++)
#pragma unroll 4
    for (int i = 0; i < 16; i++)
      sb[w][m][i * 64 + lane] = vh[((size_t)h * 2048 + (n0 + m) * 16 + i) * 64 + lane];
  a0 = 0.f; a1 = 0.f;
#pragma unroll 4
  for (int i = 0; i < 1024; i++) {
    float wv = Wcv[i * 64 + lane];
    a0 += sb[w][0][i] * wv;
    a1 += sb[w][1][i] * wv;
  }
  vcT[h * 8192 + lane * 128 + n0] = f32_to_bf16(a0);
  vcT[h * 8192 + lane * 128 + n0 + 1] = f32_to_bf16(a1);
}

// ---------------- gates ----------------
__global__ __launch_bounds__(256) void gates_k(const float* __restrict__ C,
                                               const float* __restrict__ Wg,
                                               const float* __restrict__ bg,
                                               float* __restrict__ gates) {
  const int w = threadIdx.x >> 6, lane = threadIdx.x & 63;
  const int t = blockIdx.x * 4 + w;
  float m = 0.f;
#pragma unroll
  for (int h = 0; h < 16; h++) m += C[(size_t)t * 3072 + h * 64 + lane];
  m *= (1.f / 16.f);
  float g0 = wred_sum(m * Wg[lane * 3 + 0]);
  float g1 = wred_sum(m * Wg[lane * 3 + 1]);
  float g2 = wred_sum(m * Wg[lane * 3 + 2]);
  if (lane == 0) {
    g0 += bg[0]; g1 += bg[1]; g2 += bg[2];
    float mx = fmaxf(g0, fmaxf(g1, g2));
    float e0 = __expf(g0 - mx), e1 = __expf(g1 - mx), e2 = __expf(g2 - mx);
    float inv = 1.f / (e0 + e1 + e2);
    gates[t * 3 + 0] = e0 * inv;
    gates[t * 3 + 1] = e1 * inv;
    gates[t * 3 + 2] = e2 * inv;
  }
}

// ---------------- cscore: MFMA scores + softmax + top-4 -> P (bf16), sel ----
// grid 2048 = 16 h x 128 q-tiles(16). 4 waves: wave w = block-cols w*32..w*32+31.
__global__ __launch_bounds__(256) void cscore_k(
    const float* __restrict__ qh, const unsigned short* __restrict__ kc_hi,
    const unsigned short* __restrict__ kc_lo, unsigned short* __restrict__ P,
    int4* __restrict__ sel) {
  __shared__ float S_s[16][132];
  const int h = blockIdx.x >> 7, t0 = (blockIdx.x & 127) * 16;
  const int tid = threadIdx.x, w = tid >> 6, lane = tid & 63;
  const int mrow = lane & 15, kgrp = lane >> 4;

  // A fragments: q rows (hi/lo split), same for all waves
  short8 a_hi[2], a_lo[2];
#pragma unroll
  for (int ks = 0; ks < 2; ks++) {
    const float* qp = &qh[(size_t)(t0 + mrow) * 1024 + h * 64 + ks * 32 + kgrp * 8];
    float4 q0 = *(const float4*)qp;
    float4 q1 = *(const float4*)(qp + 4);
    float qq[8] = {q0.x, q0.y, q0.z, q0.w, q1.x, q1.y, q1.z, q1.w};
#pragma unroll
    for (int j = 0; j < 8; j++) {
      unsigned short hb = f32_to_bf16(qq[j]);
      a_hi[ks][j] = (short)hb;
      a_lo[ks][j] = (short)f32_to_bf16(qq[j] - bf16_to_f32(hb));
    }
  }
  floatx4 zero = {0.f, 0.f, 0.f, 0.f};
  floatx4 acc[2] = {zero, zero};
#pragma unroll
  for (int ni = 0; ni < 2; ni++) {
    const int nb = w * 32 + ni * 16 + mrow;
#pragma unroll
    for (int ks = 0; ks < 2; ks++) {
      const size_t off = ((size_t)h * 128 + nb) * 64 + ks * 32 + kgrp * 8;
      short8 b_hi = *(const short8*)&kc_hi[off];
      short8 b_lo = *(const short8*)&kc_lo[off];
      acc[ni] = __builtin_amdgcn_mfma_f32_16x16x32_bf16(a_hi[ks], b_hi, acc[ni], 0, 0, 0);
      acc[ni] = __builtin_amdgcn_mfma_f32_16x16x32_bf16(a_lo[ks], b_hi, acc[ni], 0, 0, 0);
      acc[ni] = __builtin_amdgcn_mfma_f32_16x16x32_bf16(a_hi[ks], b_lo, acc[ni], 0, 0, 0);
    }
  }
  // scatter to LDS with scale + causal block mask (D: col=lane&15, row=kgrp*4+r)
#pragma unroll
  for (int ni = 0; ni < 2; ni++) {
    const int n = w * 32 + ni * 16 + mrow;
#pragma unroll
    for (int r = 0; r < 4; r++) {
      const int row = kgrp * 4 + r;
      const int count = (t0 + row) >> 4;
      S_s[row][n] = (n < count) ? acc[ni][r] * 0.125f : NEGC;
    }
  }
  __syncthreads();

  // each wave: softmax + top-4 for 4 queries
  for (int qq = 0; qq < 4; qq++) {
    const int row = w * 4 + qq, t = t0 + row, count = t >> 4;
    const float2 sv = *(const float2*)&S_s[row][2 * lane];
    const float s0 = sv.x, s1 = sv.y;
    const float M = wred_max(fmaxf(s0, s1));
    const float e0 = __expf(s0 - M), e1 = __expf(s1 - M);
    const float inv = 1.f / wred_sum(e0 + e1);
    ushort2 pv;
    pv.x = (count == 0) ? (unsigned short)0 : f32_to_bf16(e0 * inv);
    pv.y = (count == 0) ? (unsigned short)0 : f32_to_bf16(e1 * inv);
    *(ushort2*)&P[(((size_t)h << 11) + t) * 128 + 2 * lane] = pv;

    float c0 = s0, c1 = s1;
    int sel0 = 0, sel1 = 0, sel2 = 0, sel3 = 0;
#pragma unroll
    for (int j = 0; j < 4; j++) {
      float bv; int bi;
      if (c0 >= c1) { bv = c0; bi = 2 * lane; } else { bv = c1; bi = 2 * lane + 1; }
#pragma unroll
      for (int o = 32; o > 0; o >>= 1) {
        const float ov = __shfl_xor(bv, o, 64);
        const int oi = __shfl_xor(bi, o, 64);
        if (ov > bv || (ov == bv && oi < bi)) { bv = ov; bi = oi; }
      }
      if (j == 0) sel0 = bi; else if (j == 1) sel1 = bi;
      else if (j == 2) sel2 = bi; else sel3 = bi;
      if (bi == 2 * lane) c0 = -FLT_MAX;
      if (bi == 2 * lane + 1) c1 = -FLT_MAX;
    }
    if (lane == 0) sel[((size_t)h << 11) + t] = make_int4(sel0, sel1, sel2, sel3);
  }
}

// ---------------- out_c = P @ vc : MFMA, fragment-direct, no LDS ----------------
// grid 256 = 16 h x 16 m-tiles(128 q). wave: 32 q (2 m-tiles), N=64, K=128.
__global__ __launch_bounds__(256) void outc_k(const unsigned short* __restrict__ P,
                                              const unsigned short* __restrict__ vcT,
                                              float* __restrict__ oc) {
  const int h = blockIdx.x >> 4, t0 = (blockIdx.x & 15) * 128;
  const int tid = threadIdx.x, w = tid >> 6, lane = tid & 63;
  const int mrow = lane & 15, kgrp = lane >> 4;
  floatx4 zero = {0.f, 0.f, 0.f, 0.f};
  floatx4 acc[2][4];
#pragma unroll
  for (int mi = 0; mi < 2; mi++)
#pragma unroll
    for (int ni = 0; ni < 4; ni++) acc[mi][ni] = zero;

#pragma unroll
  for (int ks = 0; ks < 4; ks++) {
    short8 a[2];
#pragma unroll
    for (int mi = 0; mi < 2; mi++) {
      const int t = t0 + w * 32 + mi * 16 + mrow;
      a[mi] = *(const short8*)&P[(((size_t)h << 11) + t) * 128 + ks * 32 + kgrp * 8];
    }
#pragma unroll
    for (int ni = 0; ni < 4; ni++) {
      const int d = ni * 16 + mrow;
      short8 b = *(const short8*)&vcT[((size_t)h * 64 + d) * 128 + ks * 32 + kgrp * 8];
      acc[0][ni] = __builtin_amdgcn_mfma_f32_16x16x32_bf16(a[0], b, acc[0][ni], 0, 0, 0);
      acc[1][ni] = __builtin_amdgcn_mfma_f32_16x16x32_bf16(a[1], b, acc[1][ni], 0, 0, 0);
    }
  }
#pragma unroll
  for (int mi = 0; mi < 2; mi++)
#pragma unroll
    for (int ni = 0; ni < 4; ni++)
#pragma unroll
      for (int r = 0; r < 4; r++)
        oc[(size_t)(t0 + w * 32 + mi * 16 + kgrp * 4 + r) * 1024 + h * 64 + ni * 16 + mrow] =
            acc[mi][ni][r];
}

// ---------------- selected + window branches + gated combine ----------------
// one wave per (h,t); block = 4 consecutive t of one head; XCD-swizzled by h.
__global__ __launch_bounds__(256) void nsa_swl(
    const float* __restrict__ qh, const float* __restrict__ kh,
    const float* __restrict__ vh, const int4* __restrict__ sel,
    const float* __restrict__ oc, const float* __restrict__ gates,
    unsigned short* __restrict__ outf) {
  __shared__ float qb[4][64];
  __shared__ float ps[4][64];
  const int bid = blockIdx.x;
  const int h = ((bid & 7) << 1) | ((bid >> 3) & 1);
  const int t = (bid >> 4) * 4 + (threadIdx.x >> 6);
  const int w = threadIdx.x >> 6, lane = threadIdx.x & 63;

  qb[w][lane] = qh[(size_t)t * 1024 + h * 64 + lane];
  const float* khh = kh + (size_t)h * 2048 * 64;
  const float* vhh = vh + (size_t)h * 2048 * 64;
  const float4* qb4 = (const float4*)qb[w];
  const int4 s4 = sel[((size_t)h << 11) + t];

  // ---- selected: one gathered token per lane
  const int g16 = lane >> 4;
  const int blk = (g16 == 0) ? s4.x : (g16 == 1) ? s4.y : (g16 == 2) ? s4.z : s4.w;
  const int tok = blk * 16 + (lane & 15);
  const float* krow = khh + (size_t)tok * 64;
  float as_ = 0.f;
#pragma unroll
  for (int j = 0; j < 16; j++) {
    const float4 kj = *(const float4*)&krow[j * 4];
    const float4 qj = qb4[j];
    as_ += qj.x * kj.x + qj.y * kj.y + qj.z * kj.z + qj.w * kj.w;
  }
  const float sv_ = (tok <= t) ? as_ * 0.125f : NEGC;
  const float Ms = wred_max(sv_);
  const float es = __expf(sv_ - Ms);
  ps[w][lane] = es * (1.f / wred_sum(es));

  float os = 0.f;
#pragma unroll
  for (int jb = 0; jb < 4; jb++) {
    const int b2 = (jb == 0) ? s4.x : (jb == 1) ? s4.y : (jb == 2) ? s4.z : s4.w;
#pragma unroll 4
    for (int l2 = 0; l2 < 16; l2++)
      os += ps[w][jb * 16 + l2] * vhh[(size_t)(b2 * 16 + l2) * 64 + lane];
  }

  // ---- sliding window: keys t-32..t, one per lane (lanes 33..63 masked)
  const int tw = t - 32 + lane;
  const int twc = min(max(tw, 0), T_LEN - 1);
  const float* kwrow = khh + (size_t)twc * 64;
  float aw = 0.f;
#pragma unroll
  for (int j = 0; j < 16; j++) {
    const float4 kj = *(const float4*)&kwrow[j * 4];
    const float4 qj = qb4[j];
    aw += qj.x * kj.x + qj.y * kj.y + qj.z * kj.z + qj.w * kj.w;
  }
  const float swv = (tw >= 0 && lane <= 32) ? aw * 0.125f : NEGC;
  const float Mw = wred_max(swv);
  const float ew = __expf(swv - Mw);
  ps[w][lane] = ew * (1.f / wred_sum(ew));  // same-wave reuse: safe (in-order LDS)

  float ol = 0.f;
#pragma unroll 4
  for (int l = 0; l <= 32; l++) {
    const int tk = max(t - 32 + l, 0);
    ol += ps[w][l] * vhh[(size_t)tk * 64 + lane];
  }

  const float ocv = oc[(size_t)t * 1024 + h * 64 + lane];
  const float g0 = gates[t * 3 + 0], g1 = gates[t * 3 + 1], g2 = gates[t * 3 + 2];
  outf[(size_t)t * DM + h * 64 + lane] = f32_to_bf16(g0 * ocv + g1 * os + g2 * ol);
}

// ---------------- launch ----------------
extern "C" void kernel_launch(void* const* d_in, const int* in_sizes, int n_in,
                              void* d_out, int out_size, void* d_ws, size_t ws_size,
                              hipStream_t stream) {
  const float* x   = (const float*)d_in[0];
  const float* Wq  = (const float*)d_in[1];
  const float* Wk  = (const float*)d_in[2];
  const float* Wv  = (const float*)d_in[3];
  const float* Wo  = (const float*)d_in[4];
  const float* Wck = (const float*)d_in[5];
  const float* Wcv = (const float*)d_in[6];
  const float* Wg  = (const float*)d_in[7];
  const float* bg  = (const float*)d_in[8];
  float* out = (float*)d_out;

  float* ws = (float*)d_ws;
  // region A [0,24 MB): C during GEMM phase; P/oc/outf after C dies
  float*          C    = ws;
  unsigned short* P    = (unsigned short*)ws;               // [0,8 MB)  16x2048x128 bf16
  float*          oc   = ws + 2097152;                      // [8,16 MB) 2048x1024 f32
  unsigned short* outf = (unsigned short*)(ws + 4194304);   // [16,20 MB) 2048x1024 bf16
  // region B [24,36 MB): Axx during GEMM; qh + small buffers after
  unsigned short* Axx   = (unsigned short*)(ws + 6291456);  // 2048x3072 bf16
  float*          qh    = ws + 6291456;                     // [24,32 MB) 2048x1024 f32
  unsigned short* kc_hi = (unsigned short*)(ws + 8388608);  // 16x128x64 bf16
  unsigned short* kc_lo = (unsigned short*)(ws + 8454144);
  unsigned short* vcT   = (unsigned short*)(ws + 8519680);  // 16x64x128 bf16
  int4*           sel   = (int4*)(ws + 8585216);            // 32768 int4
  float*          gates = ws + 8716288;                     // 2048x3 f32
  unsigned short* Wot   = (unsigned short*)(ws + 8722432);  // 1024x1024 bf16
  // region C [36,54 MB): Bqkv during GEMM; kh/vh after
  unsigned short* Bqkv = (unsigned short*)(ws + 9437184);   // 3072x3072 bf16
  float*          kh   = ws + 9437184;                      // [36,44 MB) 16x2048x64 f32
  float*          vh   = ws + 11534336;                     // [44,52 MB)

  // 1. bf16x3 split operands
  cast_x_k<<<2048, 256, 0, stream>>>(x, Axx);
  cast_wt3<<<dim3(32, 32), dim3(32, 8), 0, stream>>>(Wq, Bqkv, 0);
  cast_wt3<<<dim3(32, 32), dim3(32, 8), 0, stream>>>(Wk, Bqkv, 1024);
  cast_wt3<<<dim3(32, 32), dim3(32, 8), 0, stream>>>(Wv, Bqkv, 2048);

  // 2. fused qkv GEMM -> C = [q | k | v] f32
  gemm_bt<<<dim3(24, 16), 256, 0, stream>>>(Axx, Bqkv, C, 2048, 3072, 3072);

  // 3. reorg + gates (consume C), then C region is reused
  reorg_qkv<<<6144, 256, 0, stream>>>(C, qh, kh, vh);
  gates_k<<<512, 256, 0, stream>>>(C, Wg, bg, gates);
  cast_wt1<<<dim3(32, 32), dim3(32, 8), 0, stream>>>(Wo, Wot);

  // 4. compression + compressed-branch pipeline
  compress_kv<<<dim3(16, 16), 256, 0, stream>>>(kh, vh, Wck, Wcv, kc_hi, kc_lo, vcT);
  cscore_k<<<2048, 256, 0, stream>>>(qh, kc_hi, kc_lo, P, sel);
  outc_k<<<256, 256, 0, stream>>>(P, vcT, oc);

  // 5. selected + window + gated combine
  nsa_swl<<<8192, 256, 0, stream>>>(qh, kh, vh, sel, oc, gates, outf);

  // 6. output projection
  gemm_bt<<<dim3(8, 16), 256, 0, stream>>>(outf, Wot, out, 2048, 1024, 1024);
}

// Round 4
// 449.161 us; speedup vs baseline: 2.0189x; 1.3239x over previous
//
#include <hip/hip_runtime.h>
#include <hip/hip_bf16.h>
#include <float.h>

#define T_LEN 2048
#define DM    1024
#define NB    128
#define NEGC  (-1e9f)

typedef __attribute__((ext_vector_type(8))) short short8;
typedef __attribute__((ext_vector_type(4))) float floatx4;

// ---------------- helpers ----------------
__device__ __forceinline__ float wred_max(float v) {
#pragma unroll
  for (int o = 32; o > 0; o >>= 1) v = fmaxf(v, __shfl_xor(v, o, 64));
  return v;
}
__device__ __forceinline__ float wred_sum(float v) {
#pragma unroll
  for (int o = 32; o > 0; o >>= 1) v += __shfl_xor(v, o, 64);
  return v;
}
__device__ __forceinline__ unsigned short f32_to_bf16(float f) {
  unsigned int b = __float_as_uint(f);
  return (unsigned short)((b + 0x7fffu + ((b >> 16) & 1u)) >> 16);
}
__device__ __forceinline__ float bf16_to_f32(unsigned short u) {
  return __uint_as_float(((unsigned int)u) << 16);
}
__device__ __forceinline__ void lds_async16(unsigned short* l, const unsigned short* g) {
  __builtin_amdgcn_global_load_lds(
      (const __attribute__((address_space(1))) unsigned int*)g,
      (__attribute__((address_space(3))) unsigned int*)l, 16, 0, 0);
}

// ---------------- bf16 MFMA GEMM: C(M,N) f32 = A(M,K)bf16 @ Bt(N,K)bf16^T ----
__global__ __launch_bounds__(256) void gemm_bt(const unsigned short* __restrict__ A,
                                               const unsigned short* __restrict__ Bt,
                                               float* __restrict__ C,
                                               int M, int N, int K) {
  __shared__ __align__(16) unsigned short As[128 * 32];
  __shared__ __align__(16) unsigned short Bs[128 * 32];
  const int tid = threadIdx.x;
  const int w = tid >> 6, lane = tid & 63;
  const int row0 = blockIdx.y * 128, col0 = blockIdx.x * 128;
  const int wr = w >> 1, wc = w & 1;
  const int r1 = tid >> 2, p1 = tid & 3;
  const int r2 = r1 + 64;

  floatx4 zero = {0.f, 0.f, 0.f, 0.f};
  floatx4 acc[4][4];
#pragma unroll
  for (int i = 0; i < 4; i++)
#pragma unroll
    for (int j = 0; j < 4; j++) acc[i][j] = zero;

  for (int k0 = 0; k0 < K; k0 += 32) {
    lds_async16(&As[w * 512],        A + (size_t)(row0 + r1) * K + k0 + p1 * 8);
    lds_async16(&As[w * 512 + 2048], A + (size_t)(row0 + r2) * K + k0 + p1 * 8);
    lds_async16(&Bs[w * 512],        Bt + (size_t)(col0 + r1) * K + k0 + p1 * 8);
    lds_async16(&Bs[w * 512 + 2048], Bt + (size_t)(col0 + r2) * K + k0 + p1 * 8);
    __syncthreads();
    short8 af[4], bf[4];
#pragma unroll
    for (int mi = 0; mi < 4; mi++)
      af[mi] = *(const short8*)&As[(wr * 64 + mi * 16 + (lane & 15)) * 32 + (lane >> 4) * 8];
#pragma unroll
    for (int ni = 0; ni < 4; ni++)
      bf[ni] = *(const short8*)&Bs[(wc * 64 + ni * 16 + (lane & 15)) * 32 + (lane >> 4) * 8];
#pragma unroll
    for (int mi = 0; mi < 4; mi++)
#pragma unroll
      for (int ni = 0; ni < 4; ni++)
        acc[mi][ni] = __builtin_amdgcn_mfma_f32_16x16x32_bf16(af[mi], bf[ni], acc[mi][ni], 0, 0, 0);
    __syncthreads();
  }
  const int ccol = lane & 15, crow4 = (lane >> 4) * 4;
#pragma unroll
  for (int mi = 0; mi < 4; mi++)
#pragma unroll
    for (int ni = 0; ni < 4; ni++) {
      float* Cp = C + (size_t)(row0 + wr * 64 + mi * 16 + crow4) * N + col0 + wc * 64 + ni * 16 + ccol;
      Cp[0] = acc[mi][ni][0];
      Cp[(size_t)N] = acc[mi][ni][1];
      Cp[(size_t)2 * N] = acc[mi][ni][2];
      Cp[(size_t)3 * N] = acc[mi][ni][3];
    }
}

// ---------------- cast x -> A'' = [x_hi | x_lo | x_hi] ----------------
__global__ __launch_bounds__(256) void cast_x_k(const float* __restrict__ x,
                                                unsigned short* __restrict__ Axx) {
  const int gid = blockIdx.x * 256 + threadIdx.x;
  float4 xv = ((const float4*)x)[gid];
  const int m = gid >> 8;
  const int c = (gid & 255) * 4;
  float vv[4] = {xv.x, xv.y, xv.z, xv.w};
  unsigned short h[4], l[4];
#pragma unroll
  for (int j = 0; j < 4; j++) {
    h[j] = f32_to_bf16(vv[j]);
    l[j] = f32_to_bf16(vv[j] - bf16_to_f32(h[j]));
  }
  ushort4 hv = make_ushort4(h[0], h[1], h[2], h[3]);
  ushort4 lv = make_ushort4(l[0], l[1], l[2], l[3]);
  *(ushort4*)&Axx[(size_t)m * 3072 + c] = hv;
  *(ushort4*)&Axx[(size_t)m * 3072 + 1024 + c] = lv;
  *(ushort4*)&Axx[(size_t)m * 3072 + 2048 + c] = hv;
}

// ---- merged: transpose-cast Wq/Wk/Wv (by blockIdx.z) into Bqkv hi/hi/lo rows ----
__global__ void cast_wt3(const float* __restrict__ Wq, const float* __restrict__ Wk,
                         const float* __restrict__ Wv, unsigned short* __restrict__ Bt) {
  __shared__ float tile[32][33];
  const float* W = (blockIdx.z == 0) ? Wq : (blockIdx.z == 1) ? Wk : Wv;
  const int n0 = blockIdx.z * 1024;
  const int kt0 = blockIdx.y * 32, nt0 = blockIdx.x * 32;
  const int tx = threadIdx.x, ty = threadIdx.y;
#pragma unroll
  for (int i = 0; i < 32; i += 8)
    tile[ty + i][tx] = W[(size_t)(kt0 + ty + i) * 1024 + nt0 + tx];
  __syncthreads();
#pragma unroll
  for (int i = 0; i < 32; i += 8) {
    const int n = nt0 + ty + i, kk = kt0 + tx;
    const float f = tile[tx][ty + i];
    const unsigned short hb = f32_to_bf16(f);
    const unsigned short lb = f32_to_bf16(f - bf16_to_f32(hb));
    const size_t base = (size_t)(n0 + n) * 3072;
    Bt[base + kk] = hb;
    Bt[base + 1024 + kk] = hb;
    Bt[base + 2048 + kk] = lb;
  }
}

__global__ void cast_wt1(const float* __restrict__ W, unsigned short* __restrict__ Bt) {
  __shared__ float tile[32][33];
  const int kt0 = blockIdx.y * 32, nt0 = blockIdx.x * 32;
  const int tx = threadIdx.x, ty = threadIdx.y;
#pragma unroll
  for (int i = 0; i < 32; i += 8)
    tile[ty + i][tx] = W[(size_t)(kt0 + ty + i) * 1024 + nt0 + tx];
  __syncthreads();
#pragma unroll
  for (int i = 0; i < 32; i += 8) {
    const int n = nt0 + ty + i, kk = kt0 + tx;
    Bt[(size_t)n * 1024 + kk] = f32_to_bf16(tile[tx][ty + i]);
  }
}

// ---- transpose-cast Wck/Wcv (1024x64) -> (64,1024) hi/lo bf16 ----
__global__ void cast_wct(const float* __restrict__ Wck, const float* __restrict__ Wcv,
                         unsigned short* __restrict__ KT_hi, unsigned short* __restrict__ KT_lo,
                         unsigned short* __restrict__ VT_hi, unsigned short* __restrict__ VT_lo) {
  __shared__ float tile[32][33];
  const float* W = blockIdx.z ? Wcv : Wck;
  unsigned short* Bh = blockIdx.z ? VT_hi : KT_hi;
  unsigned short* Bl = blockIdx.z ? VT_lo : KT_lo;
  const int kt0 = blockIdx.y * 32, nt0 = blockIdx.x * 32;
  const int tx = threadIdx.x, ty = threadIdx.y;
#pragma unroll
  for (int i = 0; i < 32; i += 8)
    tile[ty + i][tx] = W[(size_t)(kt0 + ty + i) * 64 + nt0 + tx];
  __syncthreads();
#pragma unroll
  for (int i = 0; i < 32; i += 8) {
    const int n = nt0 + ty + i, kk = kt0 + tx;
    const float f = tile[tx][ty + i];
    const unsigned short hb = f32_to_bf16(f);
    Bh[(size_t)n * 1024 + kk] = hb;
    Bl[(size_t)n * 1024 + kk] = f32_to_bf16(f - bf16_to_f32(hb));
  }
}

// ---------------- reorg: C(t,3072) -> qh (T,1024), kh/vh (H,T,64) ----------------
__global__ __launch_bounds__(256) void reorg_qkv(const float* __restrict__ C,
                                                 float* __restrict__ qh,
                                                 float* __restrict__ kh,
                                                 float* __restrict__ vh) {
  const int gid = blockIdx.x * 256 + threadIdx.x;
  const int t = gid / 768;
  const int c = (gid - t * 768) * 4;
  float4 val = *(const float4*)&C[(size_t)t * 3072 + c];
  if (c < 1024) {
    *(float4*)&qh[(size_t)t * 1024 + c] = val;
  } else {
    const int h = (c >> 6) & 15, d = c & 63;
    float* dst = (c < 2048) ? kh : vh;
    *(float4*)&dst[((size_t)h * 2048 + t) * 64 + d] = val;
  }
}

// ---------------- compress via MFMA ----------------
// A = kh|vh viewed as (2048, 1024); B = WckT|WcvT hi/lo (64, 1024) bf16.
// grid (32, 2): x = 64-row M-tile, y = 0:k (hi/lo out) 1:v (transposed bf16 out).
// No LDS, no barriers; 3-MFMA hi/lo split keeps fp32-level accuracy.
__global__ __launch_bounds__(256) void compress_mfma(
    const float* __restrict__ kh, const float* __restrict__ vh,
    const unsigned short* __restrict__ KT_hi, const unsigned short* __restrict__ KT_lo,
    const unsigned short* __restrict__ VT_hi, const unsigned short* __restrict__ VT_lo,
    unsigned short* __restrict__ kc_hi, unsigned short* __restrict__ kc_lo,
    unsigned short* __restrict__ vcT) {
  const int isv = blockIdx.y;
  const float* A = isv ? vh : kh;
  const unsigned short* Bh = isv ? VT_hi : KT_hi;
  const unsigned short* Bl = isv ? VT_lo : KT_lo;
  const int tid = threadIdx.x, w = tid >> 6, lane = tid & 63;
  const int mrow = lane & 15, kgrp = lane >> 4;
  const int m0 = blockIdx.x * 64 + w * 16;  // this wave's 16 A-rows

  floatx4 zero = {0.f, 0.f, 0.f, 0.f};
  floatx4 acc[4] = {zero, zero, zero, zero};

  for (int k0 = 0; k0 < 1024; k0 += 32) {
    // A fragment: row m0+mrow, k = k0 + kgrp*8 .. +8, cast to hi/lo
    const float* ap = &A[(size_t)(m0 + mrow) * 1024 + k0 + kgrp * 8];
    float4 q0 = *(const float4*)ap;
    float4 q1 = *(const float4*)(ap + 4);
    float qq[8] = {q0.x, q0.y, q0.z, q0.w, q1.x, q1.y, q1.z, q1.w};
    short8 a_hi, a_lo;
#pragma unroll
    for (int j = 0; j < 8; j++) {
      unsigned short hb = f32_to_bf16(qq[j]);
      a_hi[j] = (short)hb;
      a_lo[j] = (short)f32_to_bf16(qq[j] - bf16_to_f32(hb));
    }
#pragma unroll
    for (int ni = 0; ni < 4; ni++) {
      const size_t boff = (size_t)(ni * 16 + mrow) * 1024 + k0 + kgrp * 8;
      short8 b_hi = *(const short8*)&Bh[boff];
      short8 b_lo = *(const short8*)&Bl[boff];
      acc[ni] = __builtin_amdgcn_mfma_f32_16x16x32_bf16(a_hi, b_hi, acc[ni], 0, 0, 0);
      acc[ni] = __builtin_amdgcn_mfma_f32_16x16x32_bf16(a_lo, b_hi, acc[ni], 0, 0, 0);
      acc[ni] = __builtin_amdgcn_mfma_f32_16x16x32_bf16(a_hi, b_lo, acc[ni], 0, 0, 0);
    }
  }
  // epilogue: D[row=kgrp*4+r within m-tile][col=mrow within n-tile]
#pragma unroll
  for (int ni = 0; ni < 4; ni++)
#pragma unroll
    for (int r = 0; r < 4; r++) {
      const int m = m0 + kgrp * 4 + r;     // h*128 + n
      const int d = ni * 16 + mrow;
      const float val = acc[ni][r];
      if (!isv) {
        const unsigned short hb = f32_to_bf16(val);
        kc_hi[(size_t)m * 64 + d] = hb;
        kc_lo[(size_t)m * 64 + d] = f32_to_bf16(val - bf16_to_f32(hb));
      } else {
        vcT[(size_t)(m >> 7) * 8192 + (size_t)d * 128 + (m & 127)] = f32_to_bf16(val);
      }
    }
}

// ---------------- gates ----------------
__global__ __launch_bounds__(256) void gates_k(const float* __restrict__ C,
                                               const float* __restrict__ Wg,
                                               const float* __restrict__ bg,
                                               float* __restrict__ gates) {
  const int w = threadIdx.x >> 6, lane = threadIdx.x & 63;
  const int t = blockIdx.x * 4 + w;
  float m = 0.f;
#pragma unroll
  for (int h = 0; h < 16; h++) m += C[(size_t)t * 3072 + h * 64 + lane];
  m *= (1.f / 16.f);
  float g0 = wred_sum(m * Wg[lane * 3 + 0]);
  float g1 = wred_sum(m * Wg[lane * 3 + 1]);
  float g2 = wred_sum(m * Wg[lane * 3 + 2]);
  if (lane == 0) {
    g0 += bg[0]; g1 += bg[1]; g2 += bg[2];
    float mx = fmaxf(g0, fmaxf(g1, g2));
    float e0 = __expf(g0 - mx), e1 = __expf(g1 - mx), e2 = __expf(g2 - mx);
    float inv = 1.f / (e0 + e1 + e2);
    gates[t * 3 + 0] = e0 * inv;
    gates[t * 3 + 1] = e1 * inv;
    gates[t * 3 + 2] = e2 * inv;
  }
}

// ---------------- cscore: MFMA scores + softmax + top-4 -> P (bf16), sel ----
__global__ __launch_bounds__(256) void cscore_k(
    const float* __restrict__ qh, const unsigned short* __restrict__ kc_hi,
    const unsigned short* __restrict__ kc_lo, unsigned short* __restrict__ P,
    int4* __restrict__ sel) {
  __shared__ float S_s[16][132];
  const int h = blockIdx.x >> 7, t0 = (blockIdx.x & 127) * 16;
  const int tid = threadIdx.x, w = tid >> 6, lane = tid & 63;
  const int mrow = lane & 15, kgrp = lane >> 4;

  short8 a_hi[2], a_lo[2];
#pragma unroll
  for (int ks = 0; ks < 2; ks++) {
    const float* qp = &qh[(size_t)(t0 + mrow) * 1024 + h * 64 + ks * 32 + kgrp * 8];
    float4 q0 = *(const float4*)qp;
    float4 q1 = *(const float4*)(qp + 4);
    float qq[8] = {q0.x, q0.y, q0.z, q0.w, q1.x, q1.y, q1.z, q1.w};
#pragma unroll
    for (int j = 0; j < 8; j++) {
      unsigned short hb = f32_to_bf16(qq[j]);
      a_hi[ks][j] = (short)hb;
      a_lo[ks][j] = (short)f32_to_bf16(qq[j] - bf16_to_f32(hb));
    }
  }
  floatx4 zero = {0.f, 0.f, 0.f, 0.f};
  floatx4 acc[2] = {zero, zero};
#pragma unroll
  for (int ni = 0; ni < 2; ni++) {
    const int nb = w * 32 + ni * 16 + mrow;
#pragma unroll
    for (int ks = 0; ks < 2; ks++) {
      const size_t off = ((size_t)h * 128 + nb) * 64 + ks * 32 + kgrp * 8;
      short8 b_hi = *(const short8*)&kc_hi[off];
      short8 b_lo = *(const short8*)&kc_lo[off];
      acc[ni] = __builtin_amdgcn_mfma_f32_16x16x32_bf16(a_hi[ks], b_hi, acc[ni], 0, 0, 0);
      acc[ni] = __builtin_amdgcn_mfma_f32_16x16x32_bf16(a_lo[ks], b_hi, acc[ni], 0, 0, 0);
      acc[ni] = __builtin_amdgcn_mfma_f32_16x16x32_bf16(a_hi[ks], b_lo, acc[ni], 0, 0, 0);
    }
  }
#pragma unroll
  for (int ni = 0; ni < 2; ni++) {
    const int n = w * 32 + ni * 16 + mrow;
#pragma unroll
    for (int r = 0; r < 4; r++) {
      const int row = kgrp * 4 + r;
      const int count = (t0 + row) >> 4;
      S_s[row][n] = (n < count) ? acc[ni][r] * 0.125f : NEGC;
    }
  }
  __syncthreads();

  for (int qq = 0; qq < 4; qq++) {
    const int row = w * 4 + qq, t = t0 + row, count = t >> 4;
    const float2 sv = *(const float2*)&S_s[row][2 * lane];
    const float s0 = sv.x, s1 = sv.y;
    const float M = wred_max(fmaxf(s0, s1));
    const float e0 = __expf(s0 - M), e1 = __expf(s1 - M);
    const float inv = 1.f / wred_sum(e0 + e1);
    ushort2 pv;
    pv.x = (count == 0) ? (unsigned short)0 : f32_to_bf16(e0 * inv);
    pv.y = (count == 0) ? (unsigned short)0 : f32_to_bf16(e1 * inv);
    *(ushort2*)&P[(((size_t)h << 11) + t) * 128 + 2 * lane] = pv;

    float c0 = s0, c1 = s1;
    int sel0 = 0, sel1 = 0, sel2 = 0, sel3 = 0;
#pragma unroll
    for (int j = 0; j < 4; j++) {
      float bv; int bi;
      if (c0 >= c1) { bv = c0; bi = 2 * lane; } else { bv = c1; bi = 2 * lane + 1; }
#pragma unroll
      for (int o = 32; o > 0; o >>= 1) {
        const float ov = __shfl_xor(bv, o, 64);
        const int oi = __shfl_xor(bi, o, 64);
        if (ov > bv || (ov == bv && oi < bi)) { bv = ov; bi = oi; }
      }
      if (j == 0) sel0 = bi; else if (j == 1) sel1 = bi;
      else if (j == 2) sel2 = bi; else sel3 = bi;
      if (bi == 2 * lane) c0 = -FLT_MAX;
      if (bi == 2 * lane + 1) c1 = -FLT_MAX;
    }
    if (lane == 0) sel[((size_t)h << 11) + t] = make_int4(sel0, sel1, sel2, sel3);
  }
}

// ---------------- out_c = P @ vc : MFMA, fragment-direct, no LDS ----------------
__global__ __launch_bounds__(256) void outc_k(const unsigned short* __restrict__ P,
                                              const unsigned short* __restrict__ vcT,
                                              float* __restrict__ oc) {
  const int h = blockIdx.x >> 4, t0 = (blockIdx.x & 15) * 128;
  const int tid = threadIdx.x, w = tid >> 6, lane = tid & 63;
  const int mrow = lane & 15, kgrp = lane >> 4;
  floatx4 zero = {0.f, 0.f, 0.f, 0.f};
  floatx4 acc[2][4];
#pragma unroll
  for (int mi = 0; mi < 2; mi++)
#pragma unroll
    for (int ni = 0; ni < 4; ni++) acc[mi][ni] = zero;

#pragma unroll
  for (int ks = 0; ks < 4; ks++) {
    short8 a[2];
#pragma unroll
    for (int mi = 0; mi < 2; mi++) {
      const int t = t0 + w * 32 + mi * 16 + mrow;
      a[mi] = *(const short8*)&P[(((size_t)h << 11) + t) * 128 + ks * 32 + kgrp * 8];
    }
#pragma unroll
    for (int ni = 0; ni < 4; ni++) {
      const int d = ni * 16 + mrow;
      short8 b = *(const short8*)&vcT[((size_t)h * 64 + d) * 128 + ks * 32 + kgrp * 8];
      acc[0][ni] = __builtin_amdgcn_mfma_f32_16x16x32_bf16(a[0], b, acc[0][ni], 0, 0, 0);
      acc[1][ni] = __builtin_amdgcn_mfma_f32_16x16x32_bf16(a[1], b, acc[1][ni], 0, 0, 0);
    }
  }
#pragma unroll
  for (int mi = 0; mi < 2; mi++)
#pragma unroll
    for (int ni = 0; ni < 4; ni++)
#pragma unroll
      for (int r = 0; r < 4; r++)
        oc[(size_t)(t0 + w * 32 + mi * 16 + kgrp * 4 + r) * 1024 + h * 64 + ni * 16 + mrow] =
            acc[mi][ni][r];
}

// ---------------- selected + window branches + gated combine ----------------
__global__ __launch_bounds__(256) void nsa_swl(
    const float* __restrict__ qh, const float* __restrict__ kh,
    const float* __restrict__ vh, const int4* __restrict__ sel,
    const float* __restrict__ oc, const float* __restrict__ gates,
    unsigned short* __restrict__ outf) {
  __shared__ float qb[4][64];
  __shared__ float ps[4][64];
  const int bid = blockIdx.x;
  const int h = ((bid & 7) << 1) | ((bid >> 3) & 1);
  const int t = (bid >> 4) * 4 + (threadIdx.x >> 6);
  const int w = threadIdx.x >> 6, lane = threadIdx.x & 63;

  qb[w][lane] = qh[(size_t)t * 1024 + h * 64 + lane];
  const float* khh = kh + (size_t)h * 2048 * 64;
  const float* vhh = vh + (size_t)h * 2048 * 64;
  const float4* qb4 = (const float4*)qb[w];
  const int4 s4 = sel[((size_t)h << 11) + t];

  const int g16 = lane >> 4;
  const int blk = (g16 == 0) ? s4.x : (g16 == 1) ? s4.y : (g16 == 2) ? s4.z : s4.w;
  const int tok = blk * 16 + (lane & 15);
  const float* krow = khh + (size_t)tok * 64;
  float as_ = 0.f;
#pragma unroll
  for (int j = 0; j < 16; j++) {
    const float4 kj = *(const float4*)&krow[j * 4];
    const float4 qj = qb4[j];
    as_ += qj.x * kj.x + qj.y * kj.y + qj.z * kj.z + qj.w * kj.w;
  }
  const float sv_ = (tok <= t) ? as_ * 0.125f : NEGC;
  const float Ms = wred_max(sv_);
  const float es = __expf(sv_ - Ms);
  ps[w][lane] = es * (1.f / wred_sum(es));

  float os = 0.f;
#pragma unroll
  for (int jb = 0; jb < 4; jb++) {
    const int b2 = (jb == 0) ? s4.x : (jb == 1) ? s4.y : (jb == 2) ? s4.z : s4.w;
#pragma unroll 4
    for (int l2 = 0; l2 < 16; l2++)
      os += ps[w][jb * 16 + l2] * vhh[(size_t)(b2 * 16 + l2) * 64 + lane];
  }

  const int tw = t - 32 + lane;
  const int twc = min(max(tw, 0), T_LEN - 1);
  const float* kwrow = khh + (size_t)twc * 64;
  float aw = 0.f;
#pragma unroll
  for (int j = 0; j < 16; j++) {
    const float4 kj = *(const float4*)&kwrow[j * 4];
    const float4 qj = qb4[j];
    aw += qj.x * kj.x + qj.y * kj.y + qj.z * kj.z + qj.w * kj.w;
  }
  const float swv = (tw >= 0 && lane <= 32) ? aw * 0.125f : NEGC;
  const float Mw = wred_max(swv);
  const float ew = __expf(swv - Mw);
  ps[w][lane] = ew * (1.f / wred_sum(ew));

  float ol = 0.f;
#pragma unroll 4
  for (int l = 0; l <= 32; l++) {
    const int tk = max(t - 32 + l, 0);
    ol += ps[w][l] * vhh[(size_t)tk * 64 + lane];
  }

  const float ocv = oc[(size_t)t * 1024 + h * 64 + lane];
  const float g0 = gates[t * 3 + 0], g1 = gates[t * 3 + 1], g2 = gates[t * 3 + 2];
  outf[(size_t)t * DM + h * 64 + lane] = f32_to_bf16(g0 * ocv + g1 * os + g2 * ol);
}

// ---------------- launch ----------------
extern "C" void kernel_launch(void* const* d_in, const int* in_sizes, int n_in,
                              void* d_out, int out_size, void* d_ws, size_t ws_size,
                              hipStream_t stream) {
  const float* x   = (const float*)d_in[0];
  const float* Wq  = (const float*)d_in[1];
  const float* Wk  = (const float*)d_in[2];
  const float* Wv  = (const float*)d_in[3];
  const float* Wo  = (const float*)d_in[4];
  const float* Wck = (const float*)d_in[5];
  const float* Wcv = (const float*)d_in[6];
  const float* Wg  = (const float*)d_in[7];
  const float* bg  = (const float*)d_in[8];
  float* out = (float*)d_out;

  float* ws = (float*)d_ws;
  // region A [0,24 MB): C during GEMM phase; P/oc/outf after C dies
  float*          C    = ws;
  unsigned short* P    = (unsigned short*)ws;               // 16x2048x128 bf16
  float*          oc   = ws + 2097152;                      // 2048x1024 f32
  unsigned short* outf = (unsigned short*)(ws + 4194304);   // 2048x1024 bf16
  // region B [24,36 MB): Axx during GEMM; qh + small buffers after
  unsigned short* Axx   = (unsigned short*)(ws + 6291456);  // 2048x3072 bf16
  float*          qh    = ws + 6291456;                     // 2048x1024 f32
  unsigned short* kc_hi = (unsigned short*)(ws + 8388608);  // 16x128x64 bf16
  unsigned short* kc_lo = (unsigned short*)(ws + 8454144);
  unsigned short* vcT   = (unsigned short*)(ws + 8519680);  // 16x64x128 bf16
  int4*           sel   = (int4*)(ws + 8585216);            // 32768 int4
  float*          gates = ws + 8716288;                     // 2048x3 f32
  unsigned short* Wot   = (unsigned short*)(ws + 8722432);  // 1024x1024 bf16
  unsigned short* WckT_hi = (unsigned short*)(ws + 9246720);  // 64x1024 bf16 each
  unsigned short* WckT_lo = (unsigned short*)(ws + 9279488);
  unsigned short* WcvT_hi = (unsigned short*)(ws + 9312256);
  unsigned short* WcvT_lo = (unsigned short*)(ws + 9345024);
  // region C [36,54 MB): Bqkv during GEMM; kh/vh after
  unsigned short* Bqkv = (unsigned short*)(ws + 9437184);   // 3072x3072 bf16
  float*          kh   = ws + 9437184;                      // 16x2048x64 f32
  float*          vh   = ws + 11534336;

  // 1. bf16x3 split operands
  cast_x_k<<<2048, 256, 0, stream>>>(x, Axx);
  cast_wt3<<<dim3(32, 32, 3), dim3(32, 8), 0, stream>>>(Wq, Wk, Wv, Bqkv);

  // 2. fused qkv GEMM -> C = [q | k | v] f32
  gemm_bt<<<dim3(24, 16), 256, 0, stream>>>(Axx, Bqkv, C, 2048, 3072, 3072);

  // 3. reorg + gates (consume C); weight casts for later stages
  reorg_qkv<<<6144, 256, 0, stream>>>(C, qh, kh, vh);
  gates_k<<<512, 256, 0, stream>>>(C, Wg, bg, gates);
  cast_wt1<<<dim3(32, 32), dim3(32, 8), 0, stream>>>(Wo, Wot);
  cast_wct<<<dim3(2, 32, 2), dim3(32, 8), 0, stream>>>(Wck, Wcv, WckT_hi, WckT_lo, WcvT_hi, WcvT_lo);

  // 4. compression (MFMA) + compressed-branch pipeline
  compress_mfma<<<dim3(32, 2), 256, 0, stream>>>(kh, vh, WckT_hi, WckT_lo, WcvT_hi, WcvT_lo,
                                                 kc_hi, kc_lo, vcT);
  cscore_k<<<2048, 256, 0, stream>>>(qh, kc_hi, kc_lo, P, sel);
  outc_k<<<256, 256, 0, stream>>>(P, vcT, oc);

  // 5. selected + window + gated combine
  nsa_swl<<<8192, 256, 0, stream>>>(qh, kh, vh, sel, oc, gates, outf);

  // 6. output projection
  gemm_bt<<<dim3(8, 16), 256, 0, stream>>>(outf, Wot, out, 2048, 1024, 1024);
}

// Round 5
// 395.579 us; speedup vs baseline: 2.2923x; 1.1355x over previous
//
#include <hip/hip_runtime.h>
#include <hip/hip_bf16.h>
#include <float.h>

#define T_LEN 2048
#define DM    1024
#define NB    128
#define NEGC  (-1e9f)

typedef __attribute__((ext_vector_type(8))) short short8;
typedef __attribute__((ext_vector_type(4))) float floatx4;
typedef _Float16 h2 __attribute__((ext_vector_type(2)));

// ---------------- helpers ----------------
__device__ __forceinline__ float wred_max(float v) {
#pragma unroll
  for (int o = 32; o > 0; o >>= 1) v = fmaxf(v, __shfl_xor(v, o, 64));
  return v;
}
__device__ __forceinline__ float wred_sum(float v) {
#pragma unroll
  for (int o = 32; o > 0; o >>= 1) v += __shfl_xor(v, o, 64);
  return v;
}
__device__ __forceinline__ unsigned short f32_to_bf16(float f) {
  unsigned int b = __float_as_uint(f);
  return (unsigned short)((b + 0x7fffu + ((b >> 16) & 1u)) >> 16);
}
__device__ __forceinline__ float bf16_to_f32(unsigned short u) {
  return __uint_as_float(((unsigned int)u) << 16);
}
__device__ __forceinline__ unsigned int pack_h2(float a, float b) {
  h2 r; r[0] = (_Float16)a; r[1] = (_Float16)b;
  return __builtin_bit_cast(unsigned int, r);
}
// dot of two f16 pairs (packed in uints) with fp32 accumulate
__device__ __forceinline__ float fdot2u(unsigned int a, unsigned int b, float c) {
#if __has_builtin(__builtin_amdgcn_fdot2)
  return __builtin_amdgcn_fdot2(__builtin_bit_cast(h2, a), __builtin_bit_cast(h2, b), c, false);
#else
  const h2 av = __builtin_bit_cast(h2, a), bv = __builtin_bit_cast(h2, b);
  return c + (float)av[0] * (float)bv[0] + (float)av[1] * (float)bv[1];
#endif
}
__device__ __forceinline__ void lds_async16(unsigned short* l, const unsigned short* g) {
  __builtin_amdgcn_global_load_lds(
      (const __attribute__((address_space(1))) unsigned int*)g,
      (__attribute__((address_space(3))) unsigned int*)l, 16, 0, 0);
}

// ---------------- bf16 MFMA GEMM: C(M,N) f32 = A(M,K)bf16 @ Bt(N,K)bf16^T ----
__global__ __launch_bounds__(256) void gemm_bt(const unsigned short* __restrict__ A,
                                               const unsigned short* __restrict__ Bt,
                                               float* __restrict__ C,
                                               int M, int N, int K) {
  __shared__ __align__(16) unsigned short As[128 * 32];
  __shared__ __align__(16) unsigned short Bs[128 * 32];
  const int tid = threadIdx.x;
  const int w = tid >> 6, lane = tid & 63;
  const int row0 = blockIdx.y * 128, col0 = blockIdx.x * 128;
  const int wr = w >> 1, wc = w & 1;
  const int r1 = tid >> 2, p1 = tid & 3;
  const int r2 = r1 + 64;

  floatx4 zero = {0.f, 0.f, 0.f, 0.f};
  floatx4 acc[4][4];
#pragma unroll
  for (int i = 0; i < 4; i++)
#pragma unroll
    for (int j = 0; j < 4; j++) acc[i][j] = zero;

  for (int k0 = 0; k0 < K; k0 += 32) {
    lds_async16(&As[w * 512],        A + (size_t)(row0 + r1) * K + k0 + p1 * 8);
    lds_async16(&As[w * 512 + 2048], A + (size_t)(row0 + r2) * K + k0 + p1 * 8);
    lds_async16(&Bs[w * 512],        Bt + (size_t)(col0 + r1) * K + k0 + p1 * 8);
    lds_async16(&Bs[w * 512 + 2048], Bt + (size_t)(col0 + r2) * K + k0 + p1 * 8);
    __syncthreads();
    short8 af[4], bf[4];
#pragma unroll
    for (int mi = 0; mi < 4; mi++)
      af[mi] = *(const short8*)&As[(wr * 64 + mi * 16 + (lane & 15)) * 32 + (lane >> 4) * 8];
#pragma unroll
    for (int ni = 0; ni < 4; ni++)
      bf[ni] = *(const short8*)&Bs[(wc * 64 + ni * 16 + (lane & 15)) * 32 + (lane >> 4) * 8];
#pragma unroll
    for (int mi = 0; mi < 4; mi++)
#pragma unroll
      for (int ni = 0; ni < 4; ni++)
        acc[mi][ni] = __builtin_amdgcn_mfma_f32_16x16x32_bf16(af[mi], bf[ni], acc[mi][ni], 0, 0, 0);
    __syncthreads();
  }
  const int ccol = lane & 15, crow4 = (lane >> 4) * 4;
#pragma unroll
  for (int mi = 0; mi < 4; mi++)
#pragma unroll
    for (int ni = 0; ni < 4; ni++) {
      float* Cp = C + (size_t)(row0 + wr * 64 + mi * 16 + crow4) * N + col0 + wc * 64 + ni * 16 + ccol;
      Cp[0] = acc[mi][ni][0];
      Cp[(size_t)N] = acc[mi][ni][1];
      Cp[(size_t)2 * N] = acc[mi][ni][2];
      Cp[(size_t)3 * N] = acc[mi][ni][3];
    }
}

// ---------------- cast x -> A'' = [x_hi | x_lo | x_hi] ----------------
__global__ __launch_bounds__(256) void cast_x_k(const float* __restrict__ x,
                                                unsigned short* __restrict__ Axx) {
  const int gid = blockIdx.x * 256 + threadIdx.x;
  float4 xv = ((const float4*)x)[gid];
  const int m = gid >> 8;
  const int c = (gid & 255) * 4;
  float vv[4] = {xv.x, xv.y, xv.z, xv.w};
  unsigned short h[4], l[4];
#pragma unroll
  for (int j = 0; j < 4; j++) {
    h[j] = f32_to_bf16(vv[j]);
    l[j] = f32_to_bf16(vv[j] - bf16_to_f32(h[j]));
  }
  ushort4 hv = make_ushort4(h[0], h[1], h[2], h[3]);
  ushort4 lv = make_ushort4(l[0], l[1], l[2], l[3]);
  *(ushort4*)&Axx[(size_t)m * 3072 + c] = hv;
  *(ushort4*)&Axx[(size_t)m * 3072 + 1024 + c] = lv;
  *(ushort4*)&Axx[(size_t)m * 3072 + 2048 + c] = hv;
}

// ---- merged: transpose-cast Wq/Wk/Wv (by blockIdx.z) into Bqkv hi/hi/lo rows ----
__global__ void cast_wt3(const float* __restrict__ Wq, const float* __restrict__ Wk,
                         const float* __restrict__ Wv, unsigned short* __restrict__ Bt) {
  __shared__ float tile[32][33];
  const float* W = (blockIdx.z == 0) ? Wq : (blockIdx.z == 1) ? Wk : Wv;
  const int n0 = blockIdx.z * 1024;
  const int kt0 = blockIdx.y * 32, nt0 = blockIdx.x * 32;
  const int tx = threadIdx.x, ty = threadIdx.y;
#pragma unroll
  for (int i = 0; i < 32; i += 8)
    tile[ty + i][tx] = W[(size_t)(kt0 + ty + i) * 1024 + nt0 + tx];
  __syncthreads();
#pragma unroll
  for (int i = 0; i < 32; i += 8) {
    const int n = nt0 + ty + i, kk = kt0 + tx;
    const float f = tile[tx][ty + i];
    const unsigned short hb = f32_to_bf16(f);
    const unsigned short lb = f32_to_bf16(f - bf16_to_f32(hb));
    const size_t base = (size_t)(n0 + n) * 3072;
    Bt[base + kk] = hb;
    Bt[base + 1024 + kk] = hb;
    Bt[base + 2048 + kk] = lb;
  }
}

__global__ void cast_wt1(const float* __restrict__ W, unsigned short* __restrict__ Bt) {
  __shared__ float tile[32][33];
  const int kt0 = blockIdx.y * 32, nt0 = blockIdx.x * 32;
  const int tx = threadIdx.x, ty = threadIdx.y;
#pragma unroll
  for (int i = 0; i < 32; i += 8)
    tile[ty + i][tx] = W[(size_t)(kt0 + ty + i) * 1024 + nt0 + tx];
  __syncthreads();
#pragma unroll
  for (int i = 0; i < 32; i += 8) {
    const int n = nt0 + ty + i, kk = kt0 + tx;
    Bt[(size_t)n * 1024 + kk] = f32_to_bf16(tile[tx][ty + i]);
  }
}

// ---- transpose-cast Wck/Wcv (1024x64) -> (64,1024) hi/lo bf16 ----
__global__ void cast_wct(const float* __restrict__ Wck, const float* __restrict__ Wcv,
                         unsigned short* __restrict__ KT_hi, unsigned short* __restrict__ KT_lo,
                         unsigned short* __restrict__ VT_hi, unsigned short* __restrict__ VT_lo) {
  __shared__ float tile[32][33];
  const float* W = blockIdx.z ? Wcv : Wck;
  unsigned short* Bh = blockIdx.z ? VT_hi : KT_hi;
  unsigned short* Bl = blockIdx.z ? VT_lo : KT_lo;
  const int kt0 = blockIdx.y * 32, nt0 = blockIdx.x * 32;
  const int tx = threadIdx.x, ty = threadIdx.y;
#pragma unroll
  for (int i = 0; i < 32; i += 8)
    tile[ty + i][tx] = W[(size_t)(kt0 + ty + i) * 64 + nt0 + tx];
  __syncthreads();
#pragma unroll
  for (int i = 0; i < 32; i += 8) {
    const int n = nt0 + ty + i, kk = kt0 + tx;
    const float f = tile[tx][ty + i];
    const unsigned short hb = f32_to_bf16(f);
    Bh[(size_t)n * 1024 + kk] = hb;
    Bl[(size_t)n * 1024 + kk] = f32_to_bf16(f - bf16_to_f32(hb));
  }
}

// ---------------- reorg: C(t,3072) -> qh f32 (T,1024), qhf f16, khf/vhf f16 (H,T,64)
__global__ __launch_bounds__(256) void reorg_qkv(const float* __restrict__ C,
                                                 float* __restrict__ qh,
                                                 unsigned short* __restrict__ qhf,
                                                 unsigned short* __restrict__ khf,
                                                 unsigned short* __restrict__ vhf) {
  const int gid = blockIdx.x * 256 + threadIdx.x;
  const int t = gid / 768;
  const int c = (gid - t * 768) * 4;
  float4 val = *(const float4*)&C[(size_t)t * 3072 + c];
  const unsigned int p0 = pack_h2(val.x, val.y);
  const unsigned int p1 = pack_h2(val.z, val.w);
  if (c < 1024) {
    *(float4*)&qh[(size_t)t * 1024 + c] = val;
    *(uint2*)&qhf[(size_t)t * 1024 + c] = make_uint2(p0, p1);
  } else {
    const int h = (c >> 6) & 15, d = c & 63;
    unsigned short* dst = (c < 2048) ? khf : vhf;
    *(uint2*)&dst[((size_t)h * 2048 + t) * 64 + d] = make_uint2(p0, p1);
  }
}

// ---------------- compress via MFMA (reads k/v straight from C) ----------------
__global__ __launch_bounds__(256) void compress_mfma(
    const float* __restrict__ C,
    const unsigned short* __restrict__ KT_hi, const unsigned short* __restrict__ KT_lo,
    const unsigned short* __restrict__ VT_hi, const unsigned short* __restrict__ VT_lo,
    unsigned short* __restrict__ kc_hi, unsigned short* __restrict__ kc_lo,
    unsigned short* __restrict__ vcT) {
  const int isv = blockIdx.y;
  const unsigned short* Bh = isv ? VT_hi : KT_hi;
  const unsigned short* Bl = isv ? VT_lo : KT_lo;
  const int tid = threadIdx.x, w = tid >> 6, lane = tid & 63;
  const int mrow = lane & 15, kgrp = lane >> 4;
  const int m0 = blockIdx.x * 64 + w * 16;
  const int m = m0 + mrow;               // h*128 + nb
  const int hh = m >> 7, nb = m & 127;
  const int cbase = 1024 + isv * 1024 + hh * 64;

  floatx4 zero = {0.f, 0.f, 0.f, 0.f};
  floatx4 acc[4] = {zero, zero, zero, zero};

  for (int k0 = 0; k0 < 1024; k0 += 32) {
    const int c = k0 + kgrp * 8;          // within-block flat index (i*64 + d)
    const float* ap = &C[(size_t)(nb * 16 + (c >> 6)) * 3072 + cbase + (c & 63)];
    float4 q0 = *(const float4*)ap;
    float4 q1 = *(const float4*)(ap + 4);
    float qq[8] = {q0.x, q0.y, q0.z, q0.w, q1.x, q1.y, q1.z, q1.w};
    short8 a_hi, a_lo;
#pragma unroll
    for (int j = 0; j < 8; j++) {
      unsigned short hb = f32_to_bf16(qq[j]);
      a_hi[j] = (short)hb;
      a_lo[j] = (short)f32_to_bf16(qq[j] - bf16_to_f32(hb));
    }
#pragma unroll
    for (int ni = 0; ni < 4; ni++) {
      const size_t boff = (size_t)(ni * 16 + mrow) * 1024 + k0 + kgrp * 8;
      short8 b_hi = *(const short8*)&Bh[boff];
      short8 b_lo = *(const short8*)&Bl[boff];
      acc[ni] = __builtin_amdgcn_mfma_f32_16x16x32_bf16(a_hi, b_hi, acc[ni], 0, 0, 0);
      acc[ni] = __builtin_amdgcn_mfma_f32_16x16x32_bf16(a_lo, b_hi, acc[ni], 0, 0, 0);
      acc[ni] = __builtin_amdgcn_mfma_f32_16x16x32_bf16(a_hi, b_lo, acc[ni], 0, 0, 0);
    }
  }
#pragma unroll
  for (int ni = 0; ni < 4; ni++)
#pragma unroll
    for (int r = 0; r < 4; r++) {
      const int mo = m0 + kgrp * 4 + r;
      const int d = ni * 16 + mrow;
      const float val = acc[ni][r];
      if (!isv) {
        const unsigned short hb = f32_to_bf16(val);
        kc_hi[(size_t)mo * 64 + d] = hb;
        kc_lo[(size_t)mo * 64 + d] = f32_to_bf16(val - bf16_to_f32(hb));
      } else {
        vcT[(size_t)(mo >> 7) * 8192 + (size_t)d * 128 + (mo & 127)] = f32_to_bf16(val);
      }
    }
}

// ---------------- gates ----------------
__global__ __launch_bounds__(256) void gates_k(const float* __restrict__ C,
                                               const float* __restrict__ Wg,
                                               const float* __restrict__ bg,
                                               float* __restrict__ gates) {
  const int w = threadIdx.x >> 6, lane = threadIdx.x & 63;
  const int t = blockIdx.x * 4 + w;
  float m = 0.f;
#pragma unroll
  for (int h = 0; h < 16; h++) m += C[(size_t)t * 3072 + h * 64 + lane];
  m *= (1.f / 16.f);
  float g0 = wred_sum(m * Wg[lane * 3 + 0]);
  float g1 = wred_sum(m * Wg[lane * 3 + 1]);
  float g2 = wred_sum(m * Wg[lane * 3 + 2]);
  if (lane == 0) {
    g0 += bg[0]; g1 += bg[1]; g2 += bg[2];
    float mx = fmaxf(g0, fmaxf(g1, g2));
    float e0 = __expf(g0 - mx), e1 = __expf(g1 - mx), e2 = __expf(g2 - mx);
    float inv = 1.f / (e0 + e1 + e2);
    gates[t * 3 + 0] = e0 * inv;
    gates[t * 3 + 1] = e1 * inv;
    gates[t * 3 + 2] = e2 * inv;
  }
}

// ---------------- cscore: MFMA scores + softmax + top-4 -> P (bf16), sel ----
__global__ __launch_bounds__(256) void cscore_k(
    const float* __restrict__ qh, const unsigned short* __restrict__ kc_hi,
    const unsigned short* __restrict__ kc_lo, unsigned short* __restrict__ P,
    int4* __restrict__ sel) {
  __shared__ float S_s[16][132];
  const int h = blockIdx.x >> 7, t0 = (blockIdx.x & 127) * 16;
  const int tid = threadIdx.x, w = tid >> 6, lane = tid & 63;
  const int mrow = lane & 15, kgrp = lane >> 4;

  short8 a_hi[2], a_lo[2];
#pragma unroll
  for (int ks = 0; ks < 2; ks++) {
    const float* qp = &qh[(size_t)(t0 + mrow) * 1024 + h * 64 + ks * 32 + kgrp * 8];
    float4 q0 = *(const float4*)qp;
    float4 q1 = *(const float4*)(qp + 4);
    float qq[8] = {q0.x, q0.y, q0.z, q0.w, q1.x, q1.y, q1.z, q1.w};
#pragma unroll
    for (int j = 0; j < 8; j++) {
      unsigned short hb = f32_to_bf16(qq[j]);
      a_hi[ks][j] = (short)hb;
      a_lo[ks][j] = (short)f32_to_bf16(qq[j] - bf16_to_f32(hb));
    }
  }
  floatx4 zero = {0.f, 0.f, 0.f, 0.f};
  floatx4 acc[2] = {zero, zero};
#pragma unroll
  for (int ni = 0; ni < 2; ni++) {
    const int nb = w * 32 + ni * 16 + mrow;
#pragma unroll
    for (int ks = 0; ks < 2; ks++) {
      const size_t off = ((size_t)h * 128 + nb) * 64 + ks * 32 + kgrp * 8;
      short8 b_hi = *(const short8*)&kc_hi[off];
      short8 b_lo = *(const short8*)&kc_lo[off];
      acc[ni] = __builtin_amdgcn_mfma_f32_16x16x32_bf16(a_hi[ks], b_hi, acc[ni], 0, 0, 0);
      acc[ni] = __builtin_amdgcn_mfma_f32_16x16x32_bf16(a_lo[ks], b_hi, acc[ni], 0, 0, 0);
      acc[ni] = __builtin_amdgcn_mfma_f32_16x16x32_bf16(a_hi[ks], b_lo, acc[ni], 0, 0, 0);
    }
  }
#pragma unroll
  for (int ni = 0; ni < 2; ni++) {
    const int n = w * 32 + ni * 16 + mrow;
#pragma unroll
    for (int r = 0; r < 4; r++) {
      const int row = kgrp * 4 + r;
      const int count = (t0 + row) >> 4;
      S_s[row][n] = (n < count) ? acc[ni][r] * 0.125f : NEGC;
    }
  }
  __syncthreads();

  for (int qq = 0; qq < 4; qq++) {
    const int row = w * 4 + qq, t = t0 + row, count = t >> 4;
    const float2 sv = *(const float2*)&S_s[row][2 * lane];
    const float s0 = sv.x, s1 = sv.y;
    const float M = wred_max(fmaxf(s0, s1));
    const float e0 = __expf(s0 - M), e1 = __expf(s1 - M);
    const float inv = 1.f / wred_sum(e0 + e1);
    ushort2 pv;
    pv.x = (count == 0) ? (unsigned short)0 : f32_to_bf16(e0 * inv);
    pv.y = (count == 0) ? (unsigned short)0 : f32_to_bf16(e1 * inv);
    *(ushort2*)&P[(((size_t)h << 11) + t) * 128 + 2 * lane] = pv;

    float c0 = s0, c1 = s1;
    int sel0 = 0, sel1 = 0, sel2 = 0, sel3 = 0;
#pragma unroll
    for (int j = 0; j < 4; j++) {
      float bv; int bi;
      if (c0 >= c1) { bv = c0; bi = 2 * lane; } else { bv = c1; bi = 2 * lane + 1; }
#pragma unroll
      for (int o = 32; o > 0; o >>= 1) {
        const float ov = __shfl_xor(bv, o, 64);
        const int oi = __shfl_xor(bi, o, 64);
        if (ov > bv || (ov == bv && oi < bi)) { bv = ov; bi = oi; }
      }
      if (j == 0) sel0 = bi; else if (j == 1) sel1 = bi;
      else if (j == 2) sel2 = bi; else sel3 = bi;
      if (bi == 2 * lane) c0 = -FLT_MAX;
      if (bi == 2 * lane + 1) c1 = -FLT_MAX;
    }
    if (lane == 0) sel[((size_t)h << 11) + t] = make_int4(sel0, sel1, sel2, sel3);
  }
}

// ---------------- out_c = P @ vc : MFMA, fragment-direct, no LDS ----------------
__global__ __launch_bounds__(256) void outc_k(const unsigned short* __restrict__ P,
                                              const unsigned short* __restrict__ vcT,
                                              float* __restrict__ oc) {
  const int h = blockIdx.x >> 4, t0 = (blockIdx.x & 15) * 128;
  const int tid = threadIdx.x, w = tid >> 6, lane = tid & 63;
  const int mrow = lane & 15, kgrp = lane >> 4;
  floatx4 zero = {0.f, 0.f, 0.f, 0.f};
  floatx4 acc[2][4];
#pragma unroll
  for (int mi = 0; mi < 2; mi++)
#pragma unroll
    for (int ni = 0; ni < 4; ni++) acc[mi][ni] = zero;

#pragma unroll
  for (int ks = 0; ks < 4; ks++) {
    short8 a[2];
#pragma unroll
    for (int mi = 0; mi < 2; mi++) {
      const int t = t0 + w * 32 + mi * 16 + mrow;
      a[mi] = *(const short8*)&P[(((size_t)h << 11) + t) * 128 + ks * 32 + kgrp * 8];
    }
#pragma unroll
    for (int ni = 0; ni < 4; ni++) {
      const int d = ni * 16 + mrow;
      short8 b = *(const short8*)&vcT[((size_t)h * 64 + d) * 128 + ks * 32 + kgrp * 8];
      acc[0][ni] = __builtin_amdgcn_mfma_f32_16x16x32_bf16(a[0], b, acc[0][ni], 0, 0, 0);
      acc[1][ni] = __builtin_amdgcn_mfma_f32_16x16x32_bf16(a[1], b, acc[1][ni], 0, 0, 0);
    }
  }
#pragma unroll
  for (int mi = 0; mi < 2; mi++)
#pragma unroll
    for (int ni = 0; ni < 4; ni++)
#pragma unroll
      for (int r = 0; r < 4; r++)
        oc[(size_t)(t0 + w * 32 + mi * 16 + kgrp * 4 + r) * 1024 + h * 64 + ni * 16 + mrow] =
            acc[mi][ni][r];
}

// ---------------- selected + window branches + gated combine (f16, high MLP) ----
// one wave per (h,t); 4 queries per block; XCD-swizzled by h.
__global__ __launch_bounds__(256) void nsa_swl(
    const unsigned short* __restrict__ qhf, const unsigned short* __restrict__ khf,
    const unsigned short* __restrict__ vhf, const int4* __restrict__ sel,
    const float* __restrict__ oc, const float* __restrict__ gates,
    unsigned short* __restrict__ outf) {
  __shared__ float ps[4][64];
  const int bid = blockIdx.x;
  const int h = ((bid & 7) << 1) | ((bid >> 3) & 1);
  const int w = threadIdx.x >> 6, lane = threadIdx.x & 63;
  const int t = (bid >> 4) * 4 + w;

  const unsigned short* khh = khf + (size_t)h * 131072;
  const unsigned short* vhh = vhf + (size_t)h * 131072;

  // q row in registers: 64 f16 = 8 uint4 (broadcast load, all lanes same addr)
  uint4 qr[8];
  {
    const uint4* qp = (const uint4*)(qhf + (size_t)t * 1024 + h * 64);
#pragma unroll
    for (int j = 0; j < 8; j++) qr[j] = qp[j];
  }
  const int4 s4 = sel[((size_t)h << 11) + t];

  // ---- selected QK (lane = gathered token)
  const int g16 = lane >> 4;
  const int blk = (g16 == 0) ? s4.x : (g16 == 1) ? s4.y : (g16 == 2) ? s4.z : s4.w;
  const int tok = blk * 16 + (lane & 15);
  {
    const uint4* kp = (const uint4*)(khh + (size_t)tok * 64);
    float a0 = 0.f, a1 = 0.f, a2 = 0.f, a3 = 0.f;
#pragma unroll
    for (int j = 0; j < 8; j++) {
      const uint4 kk = kp[j];
      a0 = fdot2u(kk.x, qr[j].x, a0);
      a1 = fdot2u(kk.y, qr[j].y, a1);
      a2 = fdot2u(kk.z, qr[j].z, a2);
      a3 = fdot2u(kk.w, qr[j].w, a3);
    }
    const float sv_ = (tok <= t) ? ((a0 + a1) + (a2 + a3)) * 0.125f : NEGC;
    const float Ms = wred_max(sv_);
    const float es = __expf(sv_ - Ms);
    ps[w][lane] = es * (1.f / wred_sum(es));
  }

  const int dd = lane & 31, s = lane >> 5;
  const float4* ps4 = (const float4*)ps[w];

  // ---- selected PV (lane = (d-pair dd, token-half s))
  float osx = 0.f, osy = 0.f;
#pragma unroll
  for (int jc = 0; jc < 8; jc++) {
    const float4 p4 = ps4[s * 8 + jc];
    const float pa[4] = {p4.x, p4.y, p4.z, p4.w};
#pragma unroll
    for (int u = 0; u < 4; u++) {
      const int idx = s * 32 + jc * 4 + u;
      const int jb = idx >> 4;
      const int b2 = (jb == 0) ? s4.x : (jb == 1) ? s4.y : (jb == 2) ? s4.z : s4.w;
      const int tok2 = b2 * 16 + (idx & 15);
      const unsigned int vv = *(const unsigned int*)(vhh + (size_t)tok2 * 64 + 2 * dd);
      const h2 v2 = __builtin_bit_cast(h2, vv);
      osx += pa[u] * (float)v2[0];
      osy += pa[u] * (float)v2[1];
    }
  }
  osx += __shfl_xor(osx, 32, 64);
  osy += __shfl_xor(osy, 32, 64);

  // ---- window QK (lane = token t-32+lane; lanes 33..63 masked)
  {
    const int tw = t - 32 + lane;
    const int twc = min(max(tw, 0), T_LEN - 1);
    const uint4* kp = (const uint4*)(khh + (size_t)twc * 64);
    float a0 = 0.f, a1 = 0.f, a2 = 0.f, a3 = 0.f;
#pragma unroll
    for (int j = 0; j < 8; j++) {
      const uint4 kk = kp[j];
      a0 = fdot2u(kk.x, qr[j].x, a0);
      a1 = fdot2u(kk.y, qr[j].y, a1);
      a2 = fdot2u(kk.z, qr[j].z, a2);
      a3 = fdot2u(kk.w, qr[j].w, a3);
    }
    const float swv = (tw >= 0 && lane <= 32) ? ((a0 + a1) + (a2 + a3)) * 0.125f : NEGC;
    const float Mw = wred_max(swv);
    const float ew = __expf(swv - Mw);
    ps[w][lane] = ew * (1.f / wred_sum(ew));  // same-wave reuse: in-order LDS
  }

  // ---- window PV (lane = (dd, s)): s=0 -> idx 0..16, s=1 -> idx 17..32
  float olx = 0.f, oly = 0.f;
#pragma unroll
  for (int j = 0; j < 17; j++) {
    const int idx = s * 17 + j;
    const int idc = min(idx, 32);
    const float p = (idx <= 32) ? ps[w][idc] : 0.f;
    const int tk = min(max(t - 32 + idx, 0), T_LEN - 1);
    const unsigned int vv = *(const unsigned int*)(vhh + (size_t)tk * 64 + 2 * dd);
    const h2 v2 = __builtin_bit_cast(h2, vv);
    olx += p * (float)v2[0];
    oly += p * (float)v2[1];
  }
  olx += __shfl_xor(olx, 32, 64);
  oly += __shfl_xor(oly, 32, 64);

  if (lane < 32) {
    const float2 ocv = *(const float2*)&oc[(size_t)t * 1024 + h * 64 + 2 * dd];
    const float g0 = gates[t * 3 + 0], g1 = gates[t * 3 + 1], g2 = gates[t * 3 + 2];
    const float r0 = g0 * ocv.x + g1 * osx + g2 * olx;
    const float r1 = g0 * ocv.y + g1 * osy + g2 * oly;
    const unsigned int pk = (unsigned int)f32_to_bf16(r0) | ((unsigned int)f32_to_bf16(r1) << 16);
    *(unsigned int*)&outf[(size_t)t * DM + h * 64 + 2 * dd] = pk;
  }
}

// ---------------- launch ----------------
extern "C" void kernel_launch(void* const* d_in, const int* in_sizes, int n_in,
                              void* d_out, int out_size, void* d_ws, size_t ws_size,
                              hipStream_t stream) {
  const float* x   = (const float*)d_in[0];
  const float* Wq  = (const float*)d_in[1];
  const float* Wk  = (const float*)d_in[2];
  const float* Wv  = (const float*)d_in[3];
  const float* Wo  = (const float*)d_in[4];
  const float* Wck = (const float*)d_in[5];
  const float* Wcv = (const float*)d_in[6];
  const float* Wg  = (const float*)d_in[7];
  const float* bg  = (const float*)d_in[8];
  float* out = (float*)d_out;

  float* ws = (float*)d_ws;
  // region A [0,24 MB): C until compress_mfma; then P/oc/outf
  float*          C    = ws;
  unsigned short* P    = (unsigned short*)ws;               // [0,8 MB)
  float*          oc   = ws + 2097152;                      // [8,16 MB)
  unsigned short* outf = (unsigned short*)(ws + 4194304);   // [16,20 MB)
  // region B [24,36 MB): Axx until qkv GEMM; then qh + smalls
  unsigned short* Axx   = (unsigned short*)(ws + 6291456);
  float*          qh    = ws + 6291456;                     // [24,32 MB)
  unsigned short* Wot   = (unsigned short*)(ws + 8388608);  // [32,34 MB)
  unsigned short* kc_hi = (unsigned short*)(ws + 8912896);  // 256 KB
  unsigned short* kc_lo = (unsigned short*)(ws + 8978432);
  unsigned short* vcT   = (unsigned short*)(ws + 9043968);
  int4*           sel   = (int4*)(ws + 9109504);            // 512 KB
  unsigned short* WckT_hi = (unsigned short*)(ws + 9240576);
  unsigned short* WckT_lo = (unsigned short*)(ws + 9273344);
  unsigned short* WcvT_hi = (unsigned short*)(ws + 9306112);
  unsigned short* WcvT_lo = (unsigned short*)(ws + 9338880);
  float*          gates   = ws + 9371648;
  // region C [36,54 MB): Bqkv until qkv GEMM; then qhf/khf/vhf f16
  unsigned short* Bqkv = (unsigned short*)(ws + 9437184);
  unsigned short* qhf  = (unsigned short*)(ws + 9437184);   // [36,40 MB)
  unsigned short* khf  = (unsigned short*)(ws + 10485760);  // [40,44 MB)
  unsigned short* vhf  = (unsigned short*)(ws + 11534336);  // [44,48 MB)

  // 1. bf16x3 split operands
  cast_x_k<<<2048, 256, 0, stream>>>(x, Axx);
  cast_wt3<<<dim3(32, 32, 3), dim3(32, 8), 0, stream>>>(Wq, Wk, Wv, Bqkv);

  // 2. fused qkv GEMM -> C = [q | k | v] f32
  gemm_bt<<<dim3(24, 16), 256, 0, stream>>>(Axx, Bqkv, C, 2048, 3072, 3072);

  // 3. reorg + gates (C stays alive for compress); weight casts
  reorg_qkv<<<6144, 256, 0, stream>>>(C, qh, qhf, khf, vhf);
  gates_k<<<512, 256, 0, stream>>>(C, Wg, bg, gates);
  cast_wt1<<<dim3(32, 32), dim3(32, 8), 0, stream>>>(Wo, Wot);
  cast_wct<<<dim3(2, 32, 2), dim3(32, 8), 0, stream>>>(Wck, Wcv, WckT_hi, WckT_lo, WcvT_hi, WcvT_lo);

  // 4. compression (MFMA, reads C) + compressed-branch pipeline (C dead after)
  compress_mfma<<<dim3(32, 2), 256, 0, stream>>>(C, WckT_hi, WckT_lo, WcvT_hi, WcvT_lo,
                                                 kc_hi, kc_lo, vcT);
  cscore_k<<<2048, 256, 0, stream>>>(qh, kc_hi, kc_lo, P, sel);
  outc_k<<<256, 256, 0, stream>>>(P, vcT, oc);

  // 5. selected + window + gated combine
  nsa_swl<<<8192, 256, 0, stream>>>(qhf, khf, vhf, sel, oc, gates, outf);

  // 6. output projection
  gemm_bt<<<dim3(8, 16), 256, 0, stream>>>(outf, Wot, out, 2048, 1024, 1024);
}

// Round 6
// 363.389 us; speedup vs baseline: 2.4954x; 1.0886x over previous
//
#include <hip/hip_runtime.h>
#include <hip/hip_bf16.h>
#include <float.h>

#define T_LEN 2048
#define DM    1024
#define NB    128
#define NEGC  (-1e9f)

typedef __attribute__((ext_vector_type(8))) short short8;
typedef __attribute__((ext_vector_type(4))) float floatx4;
typedef _Float16 h2 __attribute__((ext_vector_type(2)));

// ---------------- helpers ----------------
__device__ __forceinline__ float wred_max(float v) {
#pragma unroll
  for (int o = 32; o > 0; o >>= 1) v = fmaxf(v, __shfl_xor(v, o, 64));
  return v;
}
__device__ __forceinline__ float wred_sum(float v) {
#pragma unroll
  for (int o = 32; o > 0; o >>= 1) v += __shfl_xor(v, o, 64);
  return v;
}
__device__ __forceinline__ unsigned short f32_to_bf16(float f) {
  unsigned int b = __float_as_uint(f);
  return (unsigned short)((b + 0x7fffu + ((b >> 16) & 1u)) >> 16);
}
__device__ __forceinline__ float bf16_to_f32(unsigned short u) {
  return __uint_as_float(((unsigned int)u) << 16);
}
__device__ __forceinline__ unsigned int pack_h2(float a, float b) {
  h2 r; r[0] = (_Float16)a; r[1] = (_Float16)b;
  return __builtin_bit_cast(unsigned int, r);
}
__device__ __forceinline__ float fdot2u(unsigned int a, unsigned int b, float c) {
#if __has_builtin(__builtin_amdgcn_fdot2)
  return __builtin_amdgcn_fdot2(__builtin_bit_cast(h2, a), __builtin_bit_cast(h2, b), c, false);
#else
  const h2 av = __builtin_bit_cast(h2, a), bv = __builtin_bit_cast(h2, b);
  return c + (float)av[0] * (float)bv[0] + (float)av[1] * (float)bv[1];
#endif
}
__device__ __forceinline__ void lds_async16(unsigned short* l, const unsigned short* g) {
  __builtin_amdgcn_global_load_lds(
      (const __attribute__((address_space(1))) unsigned int*)g,
      (__attribute__((address_space(3))) unsigned int*)l, 16, 0, 0);
}

// ---------------- bf16 MFMA GEMM: C(M,N) = A(M,K)@Bt(N,K)^T, strided ----------
__global__ __launch_bounds__(256) void gemm_bt(const unsigned short* __restrict__ A,
                                               const unsigned short* __restrict__ Bt,
                                               float* __restrict__ C,
                                               int K, int lda, int ldc) {
  __shared__ __align__(16) unsigned short As[128 * 32];
  __shared__ __align__(16) unsigned short Bs[128 * 32];
  const int tid = threadIdx.x;
  const int w = tid >> 6, lane = tid & 63;
  const int row0 = blockIdx.y * 128, col0 = blockIdx.x * 128;
  const int wr = w >> 1, wc = w & 1;
  const int r1 = tid >> 2, p1 = tid & 3;
  const int r2 = r1 + 64;

  floatx4 zero = {0.f, 0.f, 0.f, 0.f};
  floatx4 acc[4][4];
#pragma unroll
  for (int i = 0; i < 4; i++)
#pragma unroll
    for (int j = 0; j < 4; j++) acc[i][j] = zero;

  for (int k0 = 0; k0 < K; k0 += 32) {
    lds_async16(&As[w * 512],        A + (size_t)(row0 + r1) * lda + k0 + p1 * 8);
    lds_async16(&As[w * 512 + 2048], A + (size_t)(row0 + r2) * lda + k0 + p1 * 8);
    lds_async16(&Bs[w * 512],        Bt + (size_t)(col0 + r1) * K + k0 + p1 * 8);
    lds_async16(&Bs[w * 512 + 2048], Bt + (size_t)(col0 + r2) * K + k0 + p1 * 8);
    __syncthreads();
    short8 af[4], bf[4];
#pragma unroll
    for (int mi = 0; mi < 4; mi++)
      af[mi] = *(const short8*)&As[(wr * 64 + mi * 16 + (lane & 15)) * 32 + (lane >> 4) * 8];
#pragma unroll
    for (int ni = 0; ni < 4; ni++)
      bf[ni] = *(const short8*)&Bs[(wc * 64 + ni * 16 + (lane & 15)) * 32 + (lane >> 4) * 8];
#pragma unroll
    for (int mi = 0; mi < 4; mi++)
#pragma unroll
      for (int ni = 0; ni < 4; ni++)
        acc[mi][ni] = __builtin_amdgcn_mfma_f32_16x16x32_bf16(af[mi], bf[ni], acc[mi][ni], 0, 0, 0);
    __syncthreads();
  }
  const int ccol = lane & 15, crow4 = (lane >> 4) * 4;
#pragma unroll
  for (int mi = 0; mi < 4; mi++)
#pragma unroll
    for (int ni = 0; ni < 4; ni++) {
      float* Cp = C + (size_t)(row0 + wr * 64 + mi * 16 + crow4) * ldc + col0 + wc * 64 + ni * 16 + ccol;
      Cp[0] = acc[mi][ni][0];
      Cp[(size_t)ldc] = acc[mi][ni][1];
      Cp[(size_t)2 * ldc] = acc[mi][ni][2];
      Cp[(size_t)3 * ldc] = acc[mi][ni][3];
    }
}

// ---------------- cast x -> A'' = [x_hi | x_lo | x_hi] ----------------
__global__ __launch_bounds__(256) void cast_x_k(const float* __restrict__ x,
                                                unsigned short* __restrict__ Axx) {
  const int gid = blockIdx.x * 256 + threadIdx.x;
  float4 xv = ((const float4*)x)[gid];
  const int m = gid >> 8;
  const int c = (gid & 255) * 4;
  float vv[4] = {xv.x, xv.y, xv.z, xv.w};
  unsigned short h[4], l[4];
#pragma unroll
  for (int j = 0; j < 4; j++) {
    h[j] = f32_to_bf16(vv[j]);
    l[j] = f32_to_bf16(vv[j] - bf16_to_f32(h[j]));
  }
  ushort4 hv = make_ushort4(h[0], h[1], h[2], h[3]);
  ushort4 lv = make_ushort4(l[0], l[1], l[2], l[3]);
  *(ushort4*)&Axx[(size_t)m * 3072 + c] = hv;
  *(ushort4*)&Axx[(size_t)m * 3072 + 1024 + c] = lv;
  *(ushort4*)&Axx[(size_t)m * 3072 + 2048 + c] = hv;
}

// ---- transpose-cast Wq/Wk (by blockIdx.z) into Bqkv hi/hi/lo rows (K=3072) ----
__global__ void cast_wt3(const float* __restrict__ Wq, const float* __restrict__ Wk,
                         unsigned short* __restrict__ Bt) {
  __shared__ float tile[32][33];
  const float* W = (blockIdx.z == 0) ? Wq : Wk;
  const int n0 = blockIdx.z * 1024;
  const int kt0 = blockIdx.y * 32, nt0 = blockIdx.x * 32;
  const int tx = threadIdx.x, ty = threadIdx.y;
#pragma unroll
  for (int i = 0; i < 32; i += 8)
    tile[ty + i][tx] = W[(size_t)(kt0 + ty + i) * 1024 + nt0 + tx];
  __syncthreads();
#pragma unroll
  for (int i = 0; i < 32; i += 8) {
    const int n = nt0 + ty + i, kk = kt0 + tx;
    const float f = tile[tx][ty + i];
    const unsigned short hb = f32_to_bf16(f);
    const unsigned short lb = f32_to_bf16(f - bf16_to_f32(hb));
    const size_t base = (size_t)(n0 + n) * 3072;
    Bt[base + kk] = hb;
    Bt[base + 1024 + kk] = hb;
    Bt[base + 2048 + kk] = lb;
  }
}

// ---- transpose-cast 1024x1024 W -> Bt (1024n x 1024k) bf16 ----
__global__ void cast_wt1(const float* __restrict__ W, unsigned short* __restrict__ Bt) {
  __shared__ float tile[32][33];
  const int kt0 = blockIdx.y * 32, nt0 = blockIdx.x * 32;
  const int tx = threadIdx.x, ty = threadIdx.y;
#pragma unroll
  for (int i = 0; i < 32; i += 8)
    tile[ty + i][tx] = W[(size_t)(kt0 + ty + i) * 1024 + nt0 + tx];
  __syncthreads();
#pragma unroll
  for (int i = 0; i < 32; i += 8) {
    const int n = nt0 + ty + i, kk = kt0 + tx;
    Bt[(size_t)n * 1024 + kk] = f32_to_bf16(tile[tx][ty + i]);
  }
}

// ---- transpose-cast Wck/Wcv (1024x64) -> (64,1024) hi/lo bf16 ----
__global__ void cast_wct(const float* __restrict__ Wck, const float* __restrict__ Wcv,
                         unsigned short* __restrict__ KT_hi, unsigned short* __restrict__ KT_lo,
                         unsigned short* __restrict__ VT_hi, unsigned short* __restrict__ VT_lo) {
  __shared__ float tile[32][33];
  const float* W = blockIdx.z ? Wcv : Wck;
  unsigned short* Bh = blockIdx.z ? VT_hi : KT_hi;
  unsigned short* Bl = blockIdx.z ? VT_lo : KT_lo;
  const int kt0 = blockIdx.y * 32, nt0 = blockIdx.x * 32;
  const int tx = threadIdx.x, ty = threadIdx.y;
#pragma unroll
  for (int i = 0; i < 32; i += 8)
    tile[ty + i][tx] = W[(size_t)(kt0 + ty + i) * 64 + nt0 + tx];
  __syncthreads();
#pragma unroll
  for (int i = 0; i < 32; i += 8) {
    const int n = nt0 + ty + i, kk = kt0 + tx;
    const float f = tile[tx][ty + i];
    const unsigned short hb = f32_to_bf16(f);
    Bh[(size_t)n * 1024 + kk] = hb;
    Bl[(size_t)n * 1024 + kk] = f32_to_bf16(f - bf16_to_f32(hb));
  }
}

// ---------------- reorg: C(t,3072) -> qh f32, qhf f16 (T,1024),
//                  khfT f16 (H, 8, T, 8)  [d-chunk-major for coalesced gathers],
//                  vhf  f16 (H, T, 64)    [row-major for coalesced PV]
__global__ __launch_bounds__(256) void reorg_qkv(const float* __restrict__ C,
                                                 float* __restrict__ qh,
                                                 unsigned short* __restrict__ qhf,
                                                 unsigned short* __restrict__ khfT,
                                                 unsigned short* __restrict__ vhf) {
  const int gid = blockIdx.x * 256 + threadIdx.x;
  const int t = gid / 768;
  const int c = (gid - t * 768) * 4;
  float4 val = *(const float4*)&C[(size_t)t * 3072 + c];
  const unsigned int p0 = pack_h2(val.x, val.y);
  const unsigned int p1 = pack_h2(val.z, val.w);
  if (c < 1024) {
    *(float4*)&qh[(size_t)t * 1024 + c] = val;
    *(uint2*)&qhf[(size_t)t * 1024 + c] = make_uint2(p0, p1);
  } else if (c < 2048) {
    const int h = (c >> 6) & 15, d = c & 63;
    const int dc = d >> 3, j = d & 7;  // j in {0,4}
    *(uint2*)&khfT[((size_t)(h * 8 + dc) * 2048 + t) * 8 + j] = make_uint2(p0, p1);
  } else {
    const int h = (c >> 6) & 15, d = c & 63;
    *(uint2*)&vhf[((size_t)h * 2048 + t) * 64 + d] = make_uint2(p0, p1);
  }
}

// ---------------- compress via MFMA (reads k/v straight from C) ----------------
__global__ __launch_bounds__(256) void compress_mfma(
    const float* __restrict__ C,
    const unsigned short* __restrict__ KT_hi, const unsigned short* __restrict__ KT_lo,
    const unsigned short* __restrict__ VT_hi, const unsigned short* __restrict__ VT_lo,
    unsigned short* __restrict__ kc_hi, unsigned short* __restrict__ kc_lo,
    unsigned short* __restrict__ vcT) {
  const int isv = blockIdx.y;
  const unsigned short* Bh = isv ? VT_hi : KT_hi;
  const unsigned short* Bl = isv ? VT_lo : KT_lo;
  const int tid = threadIdx.x, w = tid >> 6, lane = tid & 63;
  const int mrow = lane & 15, kgrp = lane >> 4;
  const int m0 = blockIdx.x * 64 + w * 16;
  const int m = m0 + mrow;               // h*128 + nb
  const int hh = m >> 7, nb = m & 127;
  const int cbase = 1024 + isv * 1024 + hh * 64;

  floatx4 zero = {0.f, 0.f, 0.f, 0.f};
  floatx4 acc[4] = {zero, zero, zero, zero};

  for (int k0 = 0; k0 < 1024; k0 += 32) {
    const int c = k0 + kgrp * 8;
    const float* ap = &C[(size_t)(nb * 16 + (c >> 6)) * 3072 + cbase + (c & 63)];
    float4 q0 = *(const float4*)ap;
    float4 q1 = *(const float4*)(ap + 4);
    float qq[8] = {q0.x, q0.y, q0.z, q0.w, q1.x, q1.y, q1.z, q1.w};
    short8 a_hi, a_lo;
#pragma unroll
    for (int j = 0; j < 8; j++) {
      unsigned short hb = f32_to_bf16(qq[j]);
      a_hi[j] = (short)hb;
      a_lo[j] = (short)f32_to_bf16(qq[j] - bf16_to_f32(hb));
    }
#pragma unroll
    for (int ni = 0; ni < 4; ni++) {
      const size_t boff = (size_t)(ni * 16 + mrow) * 1024 + k0 + kgrp * 8;
      short8 b_hi = *(const short8*)&Bh[boff];
      short8 b_lo = *(const short8*)&Bl[boff];
      acc[ni] = __builtin_amdgcn_mfma_f32_16x16x32_bf16(a_hi, b_hi, acc[ni], 0, 0, 0);
      acc[ni] = __builtin_amdgcn_mfma_f32_16x16x32_bf16(a_lo, b_hi, acc[ni], 0, 0, 0);
      acc[ni] = __builtin_amdgcn_mfma_f32_16x16x32_bf16(a_hi, b_lo, acc[ni], 0, 0, 0);
    }
  }
#pragma unroll
  for (int ni = 0; ni < 4; ni++)
#pragma unroll
    for (int r = 0; r < 4; r++) {
      const int mo = m0 + kgrp * 4 + r;
      const int d = ni * 16 + mrow;
      const float val = acc[ni][r];
      if (!isv) {
        const unsigned short hb = f32_to_bf16(val);
        kc_hi[(size_t)mo * 64 + d] = hb;
        kc_lo[(size_t)mo * 64 + d] = f32_to_bf16(val - bf16_to_f32(hb));
      } else {
        vcT[(size_t)(mo >> 7) * 8192 + (size_t)d * 128 + (mo & 127)] = f32_to_bf16(val);
      }
    }
}

// ---------------- gates ----------------
__global__ __launch_bounds__(256) void gates_k(const float* __restrict__ C,
                                               const float* __restrict__ Wg,
                                               const float* __restrict__ bg,
                                               float* __restrict__ gates) {
  const int w = threadIdx.x >> 6, lane = threadIdx.x & 63;
  const int t = blockIdx.x * 4 + w;
  float m = 0.f;
#pragma unroll
  for (int h = 0; h < 16; h++) m += C[(size_t)t * 3072 + h * 64 + lane];
  m *= (1.f / 16.f);
  float g0 = wred_sum(m * Wg[lane * 3 + 0]);
  float g1 = wred_sum(m * Wg[lane * 3 + 1]);
  float g2 = wred_sum(m * Wg[lane * 3 + 2]);
  if (lane == 0) {
    g0 += bg[0]; g1 += bg[1]; g2 += bg[2];
    float mx = fmaxf(g0, fmaxf(g1, g2));
    float e0 = __expf(g0 - mx), e1 = __expf(g1 - mx), e2 = __expf(g2 - mx);
    float inv = 1.f / (e0 + e1 + e2);
    gates[t * 3 + 0] = e0 * inv;
    gates[t * 3 + 1] = e1 * inv;
    gates[t * 3 + 2] = e2 * inv;
  }
}

// ---------------- cscore: MFMA scores + softmax + top-4 -> P (bf16), sel ----
__global__ __launch_bounds__(256) void cscore_k(
    const float* __restrict__ qh, const unsigned short* __restrict__ kc_hi,
    const unsigned short* __restrict__ kc_lo, unsigned short* __restrict__ P,
    int4* __restrict__ sel) {
  __shared__ float S_s[16][132];
  const int h = blockIdx.x >> 7, t0 = (blockIdx.x & 127) * 16;
  const int tid = threadIdx.x, w = tid >> 6, lane = tid & 63;
  const int mrow = lane & 15, kgrp = lane >> 4;

  short8 a_hi[2], a_lo[2];
#pragma unroll
  for (int ks = 0; ks < 2; ks++) {
    const float* qp = &qh[(size_t)(t0 + mrow) * 1024 + h * 64 + ks * 32 + kgrp * 8];
    float4 q0 = *(const float4*)qp;
    float4 q1 = *(const float4*)(qp + 4);
    float qq[8] = {q0.x, q0.y, q0.z, q0.w, q1.x, q1.y, q1.z, q1.w};
#pragma unroll
    for (int j = 0; j < 8; j++) {
      unsigned short hb = f32_to_bf16(qq[j]);
      a_hi[ks][j] = (short)hb;
      a_lo[ks][j] = (short)f32_to_bf16(qq[j] - bf16_to_f32(hb));
    }
  }
  floatx4 zero = {0.f, 0.f, 0.f, 0.f};
  floatx4 acc[2] = {zero, zero};
#pragma unroll
  for (int ni = 0; ni < 2; ni++) {
    const int nb = w * 32 + ni * 16 + mrow;
#pragma unroll
    for (int ks = 0; ks < 2; ks++) {
      const size_t off = ((size_t)h * 128 + nb) * 64 + ks * 32 + kgrp * 8;
      short8 b_hi = *(const short8*)&kc_hi[off];
      short8 b_lo = *(const short8*)&kc_lo[off];
      acc[ni] = __builtin_amdgcn_mfma_f32_16x16x32_bf16(a_hi[ks], b_hi, acc[ni], 0, 0, 0);
      acc[ni] = __builtin_amdgcn_mfma_f32_16x16x32_bf16(a_lo[ks], b_hi, acc[ni], 0, 0, 0);
      acc[ni] = __builtin_amdgcn_mfma_f32_16x16x32_bf16(a_hi[ks], b_lo, acc[ni], 0, 0, 0);
    }
  }
#pragma unroll
  for (int ni = 0; ni < 2; ni++) {
    const int n = w * 32 + ni * 16 + mrow;
#pragma unroll
    for (int r = 0; r < 4; r++) {
      const int row = kgrp * 4 + r;
      const int count = (t0 + row) >> 4;
      S_s[row][n] = (n < count) ? acc[ni][r] * 0.125f : NEGC;
    }
  }
  __syncthreads();

  for (int qq = 0; qq < 4; qq++) {
    const int row = w * 4 + qq, t = t0 + row, count = t >> 4;
    const float2 sv = *(const float2*)&S_s[row][2 * lane];
    const float s0 = sv.x, s1 = sv.y;
    const float M = wred_max(fmaxf(s0, s1));
    const float e0 = __expf(s0 - M), e1 = __expf(s1 - M);
    const float inv = 1.f / wred_sum(e0 + e1);
    ushort2 pv;
    pv.x = (count == 0) ? (unsigned short)0 : f32_to_bf16(e0 * inv);
    pv.y = (count == 0) ? (unsigned short)0 : f32_to_bf16(e1 * inv);
    *(ushort2*)&P[(((size_t)h << 11) + t) * 128 + 2 * lane] = pv;

    float c0 = s0, c1 = s1;
    int sel0 = 0, sel1 = 0, sel2 = 0, sel3 = 0;
#pragma unroll
    for (int j = 0; j < 4; j++) {
      float bv; int bi;
      if (c0 >= c1) { bv = c0; bi = 2 * lane; } else { bv = c1; bi = 2 * lane + 1; }
#pragma unroll
      for (int o = 32; o > 0; o >>= 1) {
        const float ov = __shfl_xor(bv, o, 64);
        const int oi = __shfl_xor(bi, o, 64);
        if (ov > bv || (ov == bv && oi < bi)) { bv = ov; bi = oi; }
      }
      if (j == 0) sel0 = bi; else if (j == 1) sel1 = bi;
      else if (j == 2) sel2 = bi; else sel3 = bi;
      if (bi == 2 * lane) c0 = -FLT_MAX;
      if (bi == 2 * lane + 1) c1 = -FLT_MAX;
    }
    if (lane == 0) sel[((size_t)h << 11) + t] = make_int4(sel0, sel1, sel2, sel3);
  }
}

// ---------------- out_c = P @ vc : MFMA, fragment-direct, no LDS ----------------
__global__ __launch_bounds__(256) void outc_k(const unsigned short* __restrict__ P,
                                              const unsigned short* __restrict__ vcT,
                                              float* __restrict__ oc) {
  const int h = blockIdx.x >> 4, t0 = (blockIdx.x & 15) * 128;
  const int tid = threadIdx.x, w = tid >> 6, lane = tid & 63;
  const int mrow = lane & 15, kgrp = lane >> 4;
  floatx4 zero = {0.f, 0.f, 0.f, 0.f};
  floatx4 acc[2][4];
#pragma unroll
  for (int mi = 0; mi < 2; mi++)
#pragma unroll
    for (int ni = 0; ni < 4; ni++) acc[mi][ni] = zero;

#pragma unroll
  for (int ks = 0; ks < 4; ks++) {
    short8 a[2];
#pragma unroll
    for (int mi = 0; mi < 2; mi++) {
      const int t = t0 + w * 32 + mi * 16 + mrow;
      a[mi] = *(const short8*)&P[(((size_t)h << 11) + t) * 128 + ks * 32 + kgrp * 8];
    }
#pragma unroll
    for (int ni = 0; ni < 4; ni++) {
      const int d = ni * 16 + mrow;
      short8 b = *(const short8*)&vcT[((size_t)h * 64 + d) * 128 + ks * 32 + kgrp * 8];
      acc[0][ni] = __builtin_amdgcn_mfma_f32_16x16x32_bf16(a[0], b, acc[0][ni], 0, 0, 0);
      acc[1][ni] = __builtin_amdgcn_mfma_f32_16x16x32_bf16(a[1], b, acc[1][ni], 0, 0, 0);
    }
  }
#pragma unroll
  for (int mi = 0; mi < 2; mi++)
#pragma unroll
    for (int ni = 0; ni < 4; ni++)
#pragma unroll
      for (int r = 0; r < 4; r++)
        oc[(size_t)(t0 + w * 32 + mi * 16 + kgrp * 4 + r) * 1024 + h * 64 + ni * 16 + mrow] =
            acc[mi][ni][r];
}

// ---------------- selected + window branches + gated combine ----------------
// khfT layout (H, 8, T, 8) makes QK gathers line-coalesced per 16-token block.
__global__ __launch_bounds__(256) void nsa_swl(
    const unsigned short* __restrict__ qhf, const unsigned short* __restrict__ khfT,
    const unsigned short* __restrict__ vhf, const int4* __restrict__ sel,
    const float* __restrict__ oc, const float* __restrict__ gates,
    unsigned short* __restrict__ outf) {
  __shared__ float ps[4][64];
  const int bid = blockIdx.x;
  const int h = ((bid & 7) << 1) | ((bid >> 3) & 1);
  const int w = threadIdx.x >> 6, lane = threadIdx.x & 63;
  const int t = (bid >> 4) * 4 + w;

  const unsigned short* kT = khfT + (size_t)h * 131072;   // h*8*2048*8
  const unsigned short* vhh = vhf + (size_t)h * 131072;

  uint4 qr[8];
  {
    const uint4* qp = (const uint4*)(qhf + (size_t)t * 1024 + h * 64);
#pragma unroll
    for (int j = 0; j < 8; j++) qr[j] = qp[j];
  }
  const int4 s4 = sel[((size_t)h << 11) + t];

  // ---- selected QK (lane = gathered token; d-chunk loads are 16B/token coalesced)
  const int g16 = lane >> 4;
  const int blk = (g16 == 0) ? s4.x : (g16 == 1) ? s4.y : (g16 == 2) ? s4.z : s4.w;
  const int tok = blk * 16 + (lane & 15);
  {
    float a0 = 0.f, a1 = 0.f, a2 = 0.f, a3 = 0.f;
#pragma unroll
    for (int dc = 0; dc < 8; dc++) {
      const uint4 kk = *(const uint4*)(kT + ((size_t)dc * 2048 + tok) * 8);
      a0 = fdot2u(kk.x, qr[dc].x, a0);
      a1 = fdot2u(kk.y, qr[dc].y, a1);
      a2 = fdot2u(kk.z, qr[dc].z, a2);
      a3 = fdot2u(kk.w, qr[dc].w, a3);
    }
    const float sv_ = (tok <= t) ? ((a0 + a1) + (a2 + a3)) * 0.125f : NEGC;
    const float Ms = wred_max(sv_);
    const float es = __expf(sv_ - Ms);
    ps[w][lane] = es * (1.f / wred_sum(es));
  }

  const int dd = lane & 31, s = lane >> 5;
  const float4* ps4 = (const float4*)ps[w];

  // ---- selected PV (lane = (d-pair dd, token-half s); row loads coalesced)
  float osx = 0.f, osy = 0.f;
#pragma unroll
  for (int jc = 0; jc < 8; jc++) {
    const float4 p4 = ps4[s * 8 + jc];
    const float pa[4] = {p4.x, p4.y, p4.z, p4.w};
#pragma unroll
    for (int u = 0; u < 4; u++) {
      const int idx = s * 32 + jc * 4 + u;
      const int jb = idx >> 4;
      const int b2 = (jb == 0) ? s4.x : (jb == 1) ? s4.y : (jb == 2) ? s4.z : s4.w;
      const int tok2 = b2 * 16 + (idx & 15);
      const unsigned int vv = *(const unsigned int*)(vhh + (size_t)tok2 * 64 + 2 * dd);
      const h2 v2 = __builtin_bit_cast(h2, vv);
      osx += pa[u] * (float)v2[0];
      osy += pa[u] * (float)v2[1];
    }
  }
  osx += __shfl_xor(osx, 32, 64);
  osy += __shfl_xor(osy, 32, 64);

  // ---- window QK (lane = token t-32+lane; contiguous tokens -> coalesced)
  {
    const int tw = t - 32 + lane;
    const int twc = min(max(tw, 0), T_LEN - 1);
    float a0 = 0.f, a1 = 0.f, a2 = 0.f, a3 = 0.f;
#pragma unroll
    for (int dc = 0; dc < 8; dc++) {
      const uint4 kk = *(const uint4*)(kT + ((size_t)dc * 2048 + twc) * 8);
      a0 = fdot2u(kk.x, qr[dc].x, a0);
      a1 = fdot2u(kk.y, qr[dc].y, a1);
      a2 = fdot2u(kk.z, qr[dc].z, a2);
      a3 = fdot2u(kk.w, qr[dc].w, a3);
    }
    const float swv = (tw >= 0 && lane <= 32) ? ((a0 + a1) + (a2 + a3)) * 0.125f : NEGC;
    const float Mw = wred_max(swv);
    const float ew = __expf(swv - Mw);
    ps[w][lane] = ew * (1.f / wred_sum(ew));  // same-wave reuse: in-order LDS
  }

  // ---- window PV (lane = (dd, s)): s=0 -> idx 0..16, s=1 -> idx 17..32
  float olx = 0.f, oly = 0.f;
#pragma unroll
  for (int j = 0; j < 17; j++) {
    const int idx = s * 17 + j;
    const int idc = min(idx, 32);
    const float p = (idx <= 32) ? ps[w][idc] : 0.f;
    const int tk = min(max(t - 32 + idx, 0), T_LEN - 1);
    const unsigned int vv = *(const unsigned int*)(vhh + (size_t)tk * 64 + 2 * dd);
    const h2 v2 = __builtin_bit_cast(h2, vv);
    olx += p * (float)v2[0];
    oly += p * (float)v2[1];
  }
  olx += __shfl_xor(olx, 32, 64);
  oly += __shfl_xor(oly, 32, 64);

  if (lane < 32) {
    const float2 ocv = *(const float2*)&oc[(size_t)t * 1024 + h * 64 + 2 * dd];
    const float g0 = gates[t * 3 + 0], g1 = gates[t * 3 + 1], g2 = gates[t * 3 + 2];
    const float r0 = g0 * ocv.x + g1 * osx + g2 * olx;
    const float r1 = g0 * ocv.y + g1 * osy + g2 * oly;
    const unsigned int pk = (unsigned int)f32_to_bf16(r0) | ((unsigned int)f32_to_bf16(r1) << 16);
    *(unsigned int*)&outf[(size_t)t * DM + h * 64 + 2 * dd] = pk;
  }
}

// ---------------- launch ----------------
extern "C" void kernel_launch(void* const* d_in, const int* in_sizes, int n_in,
                              void* d_out, int out_size, void* d_ws, size_t ws_size,
                              hipStream_t stream) {
  const float* x   = (const float*)d_in[0];
  const float* Wq  = (const float*)d_in[1];
  const float* Wk  = (const float*)d_in[2];
  const float* Wv  = (const float*)d_in[3];
  const float* Wo  = (const float*)d_in[4];
  const float* Wck = (const float*)d_in[5];
  const float* Wcv = (const float*)d_in[6];
  const float* Wg  = (const float*)d_in[7];
  const float* bg  = (const float*)d_in[8];
  float* out = (float*)d_out;

  float* ws = (float*)d_ws;
  // region A [0,24 MB): C until compress_mfma; then P/oc/outf
  float*          C    = ws;
  unsigned short* P    = (unsigned short*)ws;               // [0,8 MB)
  float*          oc   = ws + 2097152;                      // [8,16 MB)
  unsigned short* outf = (unsigned short*)(ws + 4194304);   // [16,20 MB)
  // region B [24,36 MB): Axx until v GEMM; then qh [24,32) + smalls [32,36)
  unsigned short* Axx   = (unsigned short*)(ws + 6291456);
  float*          qh    = ws + 6291456;                     // [24,32 MB)
  unsigned short* Wot   = (unsigned short*)(ws + 8388608);  // [32,34 MB)
  unsigned short* kc_hi = (unsigned short*)(ws + 8912896);  // [34 MB ...)
  unsigned short* kc_lo = (unsigned short*)(ws + 8978432);
  unsigned short* vcT   = (unsigned short*)(ws + 9043968);
  int4*           sel   = (int4*)(ws + 9109504);
  unsigned short* WckT_hi = (unsigned short*)(ws + 9240576);
  unsigned short* WckT_lo = (unsigned short*)(ws + 9273344);
  unsigned short* WcvT_hi = (unsigned short*)(ws + 9306112);
  unsigned short* WcvT_lo = (unsigned short*)(ws + 9338880);
  float*          gates   = ws + 9371648;
  // region C [36,48 MB): Bqkv until qk GEMM; then qhf/khfT/vhf f16
  unsigned short* Bqkv = (unsigned short*)(ws + 9437184);   // 2048x3072 bf16, 12 MB
  unsigned short* qhf  = (unsigned short*)(ws + 9437184);   // [36,40 MB)
  unsigned short* khfT = (unsigned short*)(ws + 10485760);  // [40,44 MB)
  unsigned short* vhf  = (unsigned short*)(ws + 11534336);  // [44,48 MB)
  // Wvt scratch lives in d_out (dead before the final GEMM writes out)
  unsigned short* Wvt = (unsigned short*)d_out;             // 1024x1024 bf16, 2 MB

  // 1. operand preparation
  cast_x_k<<<2048, 256, 0, stream>>>(x, Axx);
  cast_wt3<<<dim3(32, 32, 2), dim3(32, 8), 0, stream>>>(Wq, Wk, Bqkv);
  cast_wt1<<<dim3(32, 32), dim3(32, 8), 0, stream>>>(Wv, Wvt);

  // 2. qk split-GEMM (K=3072, 256 blocks) + v plain GEMM (K=1024)
  gemm_bt<<<dim3(16, 16), 256, 0, stream>>>(Axx, Bqkv, C, 3072, 3072, 3072);
  gemm_bt<<<dim3(8, 16), 256, 0, stream>>>(Axx, Wvt, C + 2048, 1024, 3072, 3072);

  // 3. reorg + gates (C stays alive for compress); late weight casts
  reorg_qkv<<<6144, 256, 0, stream>>>(C, qh, qhf, khfT, vhf);
  gates_k<<<512, 256, 0, stream>>>(C, Wg, bg, gates);
  cast_wt1<<<dim3(32, 32), dim3(32, 8), 0, stream>>>(Wo, Wot);
  cast_wct<<<dim3(2, 32, 2), dim3(32, 8), 0, stream>>>(Wck, Wcv, WckT_hi, WckT_lo, WcvT_hi, WcvT_lo);

  // 4. compression (MFMA, reads C) + compressed-branch pipeline (C dead after)
  compress_mfma<<<dim3(32, 2), 256, 0, stream>>>(C, WckT_hi, WckT_lo, WcvT_hi, WcvT_lo,
                                                 kc_hi, kc_lo, vcT);
  cscore_k<<<2048, 256, 0, stream>>>(qh, kc_hi, kc_lo, P, sel);
  outc_k<<<256, 256, 0, stream>>>(P, vcT, oc);

  // 5. selected + window + gated combine
  nsa_swl<<<8192, 256, 0, stream>>>(qhf, khfT, vhf, sel, oc, gates, outf);

  // 6. output projection
  gemm_bt<<<dim3(8, 16), 256, 0, stream>>>(outf, Wot, out, 1024, 1024, 1024);
}

// Round 8
// 356.408 us; speedup vs baseline: 2.5443x; 1.0196x over previous
//
#include <hip/hip_runtime.h>
#include <hip/hip_bf16.h>
#include <float.h>

#define T_LEN 2048
#define DM    1024
#define NB    128
#define NEGC  (-1e9f)

typedef __attribute__((ext_vector_type(8))) short short8;
typedef __attribute__((ext_vector_type(4))) float floatx4;
typedef _Float16 h2 __attribute__((ext_vector_type(2)));

// ---------------- helpers ----------------
__device__ __forceinline__ float wred_max(float v) {
#pragma unroll
  for (int o = 32; o > 0; o >>= 1) v = fmaxf(v, __shfl_xor(v, o, 64));
  return v;
}
__device__ __forceinline__ float wred_sum(float v) {
#pragma unroll
  for (int o = 32; o > 0; o >>= 1) v += __shfl_xor(v, o, 64);
  return v;
}
__device__ __forceinline__ unsigned short f32_to_bf16(float f) {
  unsigned int b = __float_as_uint(f);
  return (unsigned short)((b + 0x7fffu + ((b >> 16) & 1u)) >> 16);
}
__device__ __forceinline__ float bf16_to_f32(unsigned short u) {
  return __uint_as_float(((unsigned int)u) << 16);
}
__device__ __forceinline__ unsigned int pack_h2(float a, float b) {
  h2 r; r[0] = (_Float16)a; r[1] = (_Float16)b;
  return __builtin_bit_cast(unsigned int, r);
}
__device__ __forceinline__ float fdot2u(unsigned int a, unsigned int b, float c) {
#if __has_builtin(__builtin_amdgcn_fdot2)
  return __builtin_amdgcn_fdot2(__builtin_bit_cast(h2, a), __builtin_bit_cast(h2, b), c, false);
#else
  const h2 av = __builtin_bit_cast(h2, a), bv = __builtin_bit_cast(h2, b);
  return c + (float)av[0] * (float)bv[0] + (float)av[1] * (float)bv[1];
#endif
}
__device__ __forceinline__ void lds_async16(unsigned short* l, const unsigned short* g) {
  __builtin_amdgcn_global_load_lds(
      (const __attribute__((address_space(1))) unsigned int*)g,
      (__attribute__((address_space(3))) unsigned int*)l, 16, 0, 0);
}

// =========== 64x128-tile bf16 MFMA GEMM core (chunk-major swizzled LDS) ======
// 256 thr = 4 waves (2 row-halves x 2 col-halves). BK=32.
// Staging: lane stages row = w*16+(lane&15), chunk = lane>>4 -> LDS addr is
// lane-contiguous (global_load_lds requirement) AND fragment reads land at
// byte kgrp*256 + mrow*16 -> bank = mrow*4 mod 32 (2-way aliasing = free).
// NOTE: bcol0 (B-row offset) and ccol0 (C-col offset) are SEPARATE — round-7
// bug was pre-offsetting Bt AND passing col0 (double offset).
__device__ __forceinline__ void gemm64_core(
    const unsigned short* __restrict__ A, const unsigned short* __restrict__ Bt,
    float* __restrict__ C, int K, int lda, int row0, int bcol0, int ccol0, int ldc,
    unsigned short* As, unsigned short* Bs) {
  const int tid = threadIdx.x;
  const int w = tid >> 6, lane = tid & 63;
  const int wr = w >> 1, wc = w & 1;
  const int mrow = lane & 15, kgrp = lane >> 4;

  const int sr = (w << 4) + mrow;          // staged row 0..63
  const int sc = kgrp;                     // staged chunk 0..3

  floatx4 zero = {0.f, 0.f, 0.f, 0.f};
  floatx4 acc[2][4];
#pragma unroll
  for (int i = 0; i < 2; i++)
#pragma unroll
    for (int j = 0; j < 4; j++) acc[i][j] = zero;

  for (int k0 = 0; k0 < K; k0 += 32) {
    lds_async16(&As[w * 512], A + (size_t)(row0 + sr) * lda + k0 + sc * 8);
    lds_async16(&Bs[w * 512], Bt + (size_t)(bcol0 + sr) * K + k0 + sc * 8);
    lds_async16(&Bs[2048 + w * 512], Bt + (size_t)(bcol0 + 64 + sr) * K + k0 + sc * 8);
    __syncthreads();
    short8 af[2], bf[4];
#pragma unroll
    for (int mi = 0; mi < 2; mi++)
      af[mi] = *(const short8*)&As[(wr * 2 + mi) * 512 + kgrp * 128 + mrow * 8];
#pragma unroll
    for (int ni = 0; ni < 4; ni++)
      bf[ni] = *(const short8*)&Bs[(wc * 4 + ni) * 512 + kgrp * 128 + mrow * 8];
#pragma unroll
    for (int mi = 0; mi < 2; mi++)
#pragma unroll
      for (int ni = 0; ni < 4; ni++)
        acc[mi][ni] = __builtin_amdgcn_mfma_f32_16x16x32_bf16(af[mi], bf[ni], acc[mi][ni], 0, 0, 0);
    __syncthreads();
  }
#pragma unroll
  for (int mi = 0; mi < 2; mi++)
#pragma unroll
    for (int ni = 0; ni < 4; ni++) {
      float* Cp = C + (size_t)(row0 + wr * 32 + mi * 16 + kgrp * 4) * ldc
                    + ccol0 + wc * 64 + ni * 16 + mrow;
      Cp[0] = acc[mi][ni][0];
      Cp[(size_t)ldc] = acc[mi][ni][1];
      Cp[(size_t)2 * ldc] = acc[mi][ni][2];
      Cp[(size_t)3 * ldc] = acc[mi][ni][3];
    }
}

// merged q|k|v GEMM: grid (24, 32). col-tiles 0..15: Bqkv (K=3072, bf16x3 split);
// col-tiles 16..23: Wvt (K=1024, plain hi). A = Axx for both (v uses x_hi cols).
__global__ __launch_bounds__(256) void qkv_gemm(const unsigned short* __restrict__ Axx,
                                                const unsigned short* __restrict__ Bqkv,
                                                const unsigned short* __restrict__ Wvt,
                                                float* __restrict__ C) {
  __shared__ __align__(16) unsigned short As[64 * 32];
  __shared__ __align__(16) unsigned short Bs[128 * 32];
  const int ct = blockIdx.x;
  const unsigned short* Bt;
  int K, bcol0;
  if (ct < 16) { Bt = Bqkv; K = 3072; bcol0 = ct * 128; }
  else         { Bt = Wvt;  K = 1024; bcol0 = (ct - 16) * 128; }
  gemm64_core(Axx, Bt, C, K, 3072, blockIdx.y * 64, bcol0, ct * 128, 3072, As, Bs);
}

// generic 64x128 GEMM (final output projection)
__global__ __launch_bounds__(256) void gemm_bt64(const unsigned short* __restrict__ A,
                                                 const unsigned short* __restrict__ Bt,
                                                 float* __restrict__ C,
                                                 int K, int lda, int ldc) {
  __shared__ __align__(16) unsigned short As[64 * 32];
  __shared__ __align__(16) unsigned short Bs[128 * 32];
  gemm64_core(A, Bt, C, K, lda, blockIdx.y * 64,
              blockIdx.x * 128, blockIdx.x * 128, ldc, As, Bs);
}

// ---------------- cast x -> A'' = [x_hi | x_lo | x_hi] ----------------
__global__ __launch_bounds__(256) void cast_x_k(const float* __restrict__ x,
                                                unsigned short* __restrict__ Axx) {
  const int gid = blockIdx.x * 256 + threadIdx.x;
  float4 xv = ((const float4*)x)[gid];
  const int m = gid >> 8;
  const int c = (gid & 255) * 4;
  float vv[4] = {xv.x, xv.y, xv.z, xv.w};
  unsigned short h[4], l[4];
#pragma unroll
  for (int j = 0; j < 4; j++) {
    h[j] = f32_to_bf16(vv[j]);
    l[j] = f32_to_bf16(vv[j] - bf16_to_f32(h[j]));
  }
  ushort4 hv = make_ushort4(h[0], h[1], h[2], h[3]);
  ushort4 lv = make_ushort4(l[0], l[1], l[2], l[3]);
  *(ushort4*)&Axx[(size_t)m * 3072 + c] = hv;
  *(ushort4*)&Axx[(size_t)m * 3072 + 1024 + c] = lv;
  *(ushort4*)&Axx[(size_t)m * 3072 + 2048 + c] = hv;
}

// ---- transpose-cast Wq/Wk (by blockIdx.z) into Bqkv hi/hi/lo rows (K=3072) ----
__global__ void cast_wt3(const float* __restrict__ Wq, const float* __restrict__ Wk,
                         unsigned short* __restrict__ Bt) {
  __shared__ float tile[32][33];
  const float* W = (blockIdx.z == 0) ? Wq : Wk;
  const int n0 = blockIdx.z * 1024;
  const int kt0 = blockIdx.y * 32, nt0 = blockIdx.x * 32;
  const int tx = threadIdx.x, ty = threadIdx.y;
#pragma unroll
  for (int i = 0; i < 32; i += 8)
    tile[ty + i][tx] = W[(size_t)(kt0 + ty + i) * 1024 + nt0 + tx];
  __syncthreads();
#pragma unroll
  for (int i = 0; i < 32; i += 8) {
    const int n = nt0 + ty + i, kk = kt0 + tx;
    const float f = tile[tx][ty + i];
    const unsigned short hb = f32_to_bf16(f);
    const unsigned short lb = f32_to_bf16(f - bf16_to_f32(hb));
    const size_t base = (size_t)(n0 + n) * 3072;
    Bt[base + kk] = hb;
    Bt[base + 1024 + kk] = hb;
    Bt[base + 2048 + kk] = lb;
  }
}

// ---- transpose-cast 1024x1024 W -> Bt (1024n x 1024k) bf16 ----
__global__ void cast_wt1(const float* __restrict__ W, unsigned short* __restrict__ Bt) {
  __shared__ float tile[32][33];
  const int kt0 = blockIdx.y * 32, nt0 = blockIdx.x * 32;
  const int tx = threadIdx.x, ty = threadIdx.y;
#pragma unroll
  for (int i = 0; i < 32; i += 8)
    tile[ty + i][tx] = W[(size_t)(kt0 + ty + i) * 1024 + nt0 + tx];
  __syncthreads();
#pragma unroll
  for (int i = 0; i < 32; i += 8) {
    const int n = nt0 + ty + i, kk = kt0 + tx;
    Bt[(size_t)n * 1024 + kk] = f32_to_bf16(tile[tx][ty + i]);
  }
}

// ---- transpose-cast Wck/Wcv (1024x64) -> (64,1024) hi/lo bf16 ----
__global__ void cast_wct(const float* __restrict__ Wck, const float* __restrict__ Wcv,
                         unsigned short* __restrict__ KT_hi, unsigned short* __restrict__ KT_lo,
                         unsigned short* __restrict__ VT_hi, unsigned short* __restrict__ VT_lo) {
  __shared__ float tile[32][33];
  const float* W = blockIdx.z ? Wcv : Wck;
  unsigned short* Bh = blockIdx.z ? VT_hi : KT_hi;
  unsigned short* Bl = blockIdx.z ? VT_lo : KT_lo;
  const int kt0 = blockIdx.y * 32, nt0 = blockIdx.x * 32;
  const int tx = threadIdx.x, ty = threadIdx.y;
#pragma unroll
  for (int i = 0; i < 32; i += 8)
    tile[ty + i][tx] = W[(size_t)(kt0 + ty + i) * 64 + nt0 + tx];
  __syncthreads();
#pragma unroll
  for (int i = 0; i < 32; i += 8) {
    const int n = nt0 + ty + i, kk = kt0 + tx;
    const float f = tile[tx][ty + i];
    const unsigned short hb = f32_to_bf16(f);
    Bh[(size_t)n * 1024 + kk] = hb;
    Bl[(size_t)n * 1024 + kk] = f32_to_bf16(f - bf16_to_f32(hb));
  }
}

// ---------------- reorg: C(t,3072) -> qh f32, qhf f16 (T,1024),
//                  khfT f16 (H, 8, T, 8), vhf f16 (H, T, 64) ----------------
__global__ __launch_bounds__(256) void reorg_qkv(const float* __restrict__ C,
                                                 float* __restrict__ qh,
                                                 unsigned short* __restrict__ qhf,
                                                 unsigned short* __restrict__ khfT,
                                                 unsigned short* __restrict__ vhf) {
  const int gid = blockIdx.x * 256 + threadIdx.x;
  const int t = gid / 768;
  const int c = (gid - t * 768) * 4;
  float4 val = *(const float4*)&C[(size_t)t * 3072 + c];
  const unsigned int p0 = pack_h2(val.x, val.y);
  const unsigned int p1 = pack_h2(val.z, val.w);
  if (c < 1024) {
    *(float4*)&qh[(size_t)t * 1024 + c] = val;
    *(uint2*)&qhf[(size_t)t * 1024 + c] = make_uint2(p0, p1);
  } else if (c < 2048) {
    const int h = (c >> 6) & 15, d = c & 63;
    const int dc = d >> 3, j = d & 7;
    *(uint2*)&khfT[((size_t)(h * 8 + dc) * 2048 + t) * 8 + j] = make_uint2(p0, p1);
  } else {
    const int h = (c >> 6) & 15, d = c & 63;
    *(uint2*)&vhf[((size_t)h * 2048 + t) * 64 + d] = make_uint2(p0, p1);
  }
}

// ---------------- compress via MFMA (reads k/v straight from C) ----------------
__global__ __launch_bounds__(256) void compress_mfma(
    const float* __restrict__ C,
    const unsigned short* __restrict__ KT_hi, const unsigned short* __restrict__ KT_lo,
    const unsigned short* __restrict__ VT_hi, const unsigned short* __restrict__ VT_lo,
    unsigned short* __restrict__ kc_hi, unsigned short* __restrict__ kc_lo,
    unsigned short* __restrict__ vcT) {
  const int isv = blockIdx.y;
  const unsigned short* Bh = isv ? VT_hi : KT_hi;
  const unsigned short* Bl = isv ? VT_lo : KT_lo;
  const int tid = threadIdx.x, w = tid >> 6, lane = tid & 63;
  const int mrow = lane & 15, kgrp = lane >> 4;
  const int m0 = blockIdx.x * 64 + w * 16;
  const int m = m0 + mrow;
  const int hh = m >> 7, nb = m & 127;
  const int cbase = 1024 + isv * 1024 + hh * 64;

  floatx4 zero = {0.f, 0.f, 0.f, 0.f};
  floatx4 acc[4] = {zero, zero, zero, zero};

  for (int k0 = 0; k0 < 1024; k0 += 32) {
    const int c = k0 + kgrp * 8;
    const float* ap = &C[(size_t)(nb * 16 + (c >> 6)) * 3072 + cbase + (c & 63)];
    float4 q0 = *(const float4*)ap;
    float4 q1 = *(const float4*)(ap + 4);
    float qq[8] = {q0.x, q0.y, q0.z, q0.w, q1.x, q1.y, q1.z, q1.w};
    short8 a_hi, a_lo;
#pragma unroll
    for (int j = 0; j < 8; j++) {
      unsigned short hb = f32_to_bf16(qq[j]);
      a_hi[j] = (short)hb;
      a_lo[j] = (short)f32_to_bf16(qq[j] - bf16_to_f32(hb));
    }
#pragma unroll
    for (int ni = 0; ni < 4; ni++) {
      const size_t boff = (size_t)(ni * 16 + mrow) * 1024 + k0 + kgrp * 8;
      short8 b_hi = *(const short8*)&Bh[boff];
      short8 b_lo = *(const short8*)&Bl[boff];
      acc[ni] = __builtin_amdgcn_mfma_f32_16x16x32_bf16(a_hi, b_hi, acc[ni], 0, 0, 0);
      acc[ni] = __builtin_amdgcn_mfma_f32_16x16x32_bf16(a_lo, b_hi, acc[ni], 0, 0, 0);
      acc[ni] = __builtin_amdgcn_mfma_f32_16x16x32_bf16(a_hi, b_lo, acc[ni], 0, 0, 0);
    }
  }
#pragma unroll
  for (int ni = 0; ni < 4; ni++)
#pragma unroll
    for (int r = 0; r < 4; r++) {
      const int mo = m0 + kgrp * 4 + r;
      const int d = ni * 16 + mrow;
      const float val = acc[ni][r];
      if (!isv) {
        const unsigned short hb = f32_to_bf16(val);
        kc_hi[(size_t)mo * 64 + d] = hb;
        kc_lo[(size_t)mo * 64 + d] = f32_to_bf16(val - bf16_to_f32(hb));
      } else {
        vcT[(size_t)(mo >> 7) * 8192 + (size_t)d * 128 + (mo & 127)] = f32_to_bf16(val);
      }
    }
}

// ---------------- gates ----------------
__global__ __launch_bounds__(256) void gates_k(const float* __restrict__ C,
                                               const float* __restrict__ Wg,
                                               const float* __restrict__ bg,
                                               float* __restrict__ gates) {
  const int w = threadIdx.x >> 6, lane = threadIdx.x & 63;
  const int t = blockIdx.x * 4 + w;
  float m = 0.f;
#pragma unroll
  for (int h = 0; h < 16; h++) m += C[(size_t)t * 3072 + h * 64 + lane];
  m *= (1.f / 16.f);
  float g0 = wred_sum(m * Wg[lane * 3 + 0]);
  float g1 = wred_sum(m * Wg[lane * 3 + 1]);
  float g2 = wred_sum(m * Wg[lane * 3 + 2]);
  if (lane == 0) {
    g0 += bg[0]; g1 += bg[1]; g2 += bg[2];
    float mx = fmaxf(g0, fmaxf(g1, g2));
    float e0 = __expf(g0 - mx), e1 = __expf(g1 - mx), e2 = __expf(g2 - mx);
    float inv = 1.f / (e0 + e1 + e2);
    gates[t * 3 + 0] = e0 * inv;
    gates[t * 3 + 1] = e1 * inv;
    gates[t * 3 + 2] = e2 * inv;
  }
}

// ---------------- cscore: MFMA scores + softmax + top-4 -> P (bf16), sel ----
__global__ __launch_bounds__(256) void cscore_k(
    const float* __restrict__ qh, const unsigned short* __restrict__ kc_hi,
    const unsigned short* __restrict__ kc_lo, unsigned short* __restrict__ P,
    int4* __restrict__ sel) {
  __shared__ float S_s[16][132];
  const int h = blockIdx.x >> 7, t0 = (blockIdx.x & 127) * 16;
  const int tid = threadIdx.x, w = tid >> 6, lane = tid & 63;
  const int mrow = lane & 15, kgrp = lane >> 4;

  short8 a_hi[2], a_lo[2];
#pragma unroll
  for (int ks = 0; ks < 2; ks++) {
    const float* qp = &qh[(size_t)(t0 + mrow) * 1024 + h * 64 + ks * 32 + kgrp * 8];
    float4 q0 = *(const float4*)qp;
    float4 q1 = *(const float4*)(qp + 4);
    float qq[8] = {q0.x, q0.y, q0.z, q0.w, q1.x, q1.y, q1.z, q1.w};
#pragma unroll
    for (int j = 0; j < 8; j++) {
      unsigned short hb = f32_to_bf16(qq[j]);
      a_hi[ks][j] = (short)hb;
      a_lo[ks][j] = (short)f32_to_bf16(qq[j] - bf16_to_f32(hb));
    }
  }
  floatx4 zero = {0.f, 0.f, 0.f, 0.f};
  floatx4 acc[2] = {zero, zero};
#pragma unroll
  for (int ni = 0; ni < 2; ni++) {
    const int nb = w * 32 + ni * 16 + mrow;
#pragma unroll
    for (int ks = 0; ks < 2; ks++) {
      const size_t off = ((size_t)h * 128 + nb) * 64 + ks * 32 + kgrp * 8;
      short8 b_hi = *(const short8*)&kc_hi[off];
      short8 b_lo = *(const short8*)&kc_lo[off];
      acc[ni] = __builtin_amdgcn_mfma_f32_16x16x32_bf16(a_hi[ks], b_hi, acc[ni], 0, 0, 0);
      acc[ni] = __builtin_amdgcn_mfma_f32_16x16x32_bf16(a_lo[ks], b_hi, acc[ni], 0, 0, 0);
      acc[ni] = __builtin_amdgcn_mfma_f32_16x16x32_bf16(a_hi[ks], b_lo, acc[ni], 0, 0, 0);
    }
  }
#pragma unroll
  for (int ni = 0; ni < 2; ni++) {
    const int n = w * 32 + ni * 16 + mrow;
#pragma unroll
    for (int r = 0; r < 4; r++) {
      const int row = kgrp * 4 + r;
      const int count = (t0 + row) >> 4;
      S_s[row][n] = (n < count) ? acc[ni][r] * 0.125f : NEGC;
    }
  }
  __syncthreads();

  for (int qq = 0; qq < 4; qq++) {
    const int row = w * 4 + qq, t = t0 + row, count = t >> 4;
    const float2 sv = *(const float2*)&S_s[row][2 * lane];
    const float s0 = sv.x, s1 = sv.y;
    const float M = wred_max(fmaxf(s0, s1));
    const float e0 = __expf(s0 - M), e1 = __expf(s1 - M);
    const float inv = 1.f / wred_sum(e0 + e1);
    ushort2 pv;
    pv.x = (count == 0) ? (unsigned short)0 : f32_to_bf16(e0 * inv);
    pv.y = (count == 0) ? (unsigned short)0 : f32_to_bf16(e1 * inv);
    *(ushort2*)&P[(((size_t)h << 11) + t) * 128 + 2 * lane] = pv;

    float c0 = s0, c1 = s1;
    int sel0 = 0, sel1 = 0, sel2 = 0, sel3 = 0;
#pragma unroll
    for (int j = 0; j < 4; j++) {
      float bv; int bi;
      if (c0 >= c1) { bv = c0; bi = 2 * lane; } else { bv = c1; bi = 2 * lane + 1; }
#pragma unroll
      for (int o = 32; o > 0; o >>= 1) {
        const float ov = __shfl_xor(bv, o, 64);
        const int oi = __shfl_xor(bi, o, 64);
        if (ov > bv || (ov == bv && oi < bi)) { bv = ov; bi = oi; }
      }
      if (j == 0) sel0 = bi; else if (j == 1) sel1 = bi;
      else if (j == 2) sel2 = bi; else sel3 = bi;
      if (bi == 2 * lane) c0 = -FLT_MAX;
      if (bi == 2 * lane + 1) c1 = -FLT_MAX;
    }
    if (lane == 0) sel[((size_t)h << 11) + t] = make_int4(sel0, sel1, sel2, sel3);
  }
}

// ---------------- out_c = P @ vc : MFMA, fragment-direct, no LDS ----------------
__global__ __launch_bounds__(256) void outc_k(const unsigned short* __restrict__ P,
                                              const unsigned short* __restrict__ vcT,
                                              float* __restrict__ oc) {
  const int h = blockIdx.x >> 4, t0 = (blockIdx.x & 15) * 128;
  const int tid = threadIdx.x, w = tid >> 6, lane = tid & 63;
  const int mrow = lane & 15, kgrp = lane >> 4;
  floatx4 zero = {0.f, 0.f, 0.f, 0.f};
  floatx4 acc[2][4];
#pragma unroll
  for (int mi = 0; mi < 2; mi++)
#pragma unroll
    for (int ni = 0; ni < 4; ni++) acc[mi][ni] = zero;

#pragma unroll
  for (int ks = 0; ks < 4; ks++) {
    short8 a[2];
#pragma unroll
    for (int mi = 0; mi < 2; mi++) {
      const int t = t0 + w * 32 + mi * 16 + mrow;
      a[mi] = *(const short8*)&P[(((size_t)h << 11) + t) * 128 + ks * 32 + kgrp * 8];
    }
#pragma unroll
    for (int ni = 0; ni < 4; ni++) {
      const int d = ni * 16 + mrow;
      short8 b = *(const short8*)&vcT[((size_t)h * 64 + d) * 128 + ks * 32 + kgrp * 8];
      acc[0][ni] = __builtin_amdgcn_mfma_f32_16x16x32_bf16(a[0], b, acc[0][ni], 0, 0, 0);
      acc[1][ni] = __builtin_amdgcn_mfma_f32_16x16x32_bf16(a[1], b, acc[1][ni], 0, 0, 0);
    }
  }
#pragma unroll
  for (int mi = 0; mi < 2; mi++)
#pragma unroll
    for (int ni = 0; ni < 4; ni++)
#pragma unroll
      for (int r = 0; r < 4; r++)
        oc[(size_t)(t0 + w * 32 + mi * 16 + kgrp * 4 + r) * 1024 + h * 64 + ni * 16 + mrow] =
            acc[mi][ni][r];
}

// ---------------- selected + window branches + gated combine ----------------
__global__ __launch_bounds__(256) void nsa_swl(
    const unsigned short* __restrict__ qhf, const unsigned short* __restrict__ khfT,
    const unsigned short* __restrict__ vhf, const int4* __restrict__ sel,
    const float* __restrict__ oc, const float* __restrict__ gates,
    unsigned short* __restrict__ outf) {
  __shared__ float ps[4][64];
  const int bid = blockIdx.x;
  const int h = ((bid & 7) << 1) | ((bid >> 3) & 1);
  const int w = threadIdx.x >> 6, lane = threadIdx.x & 63;
  const int t = (bid >> 4) * 4 + w;

  const unsigned short* kT = khfT + (size_t)h * 131072;
  const unsigned short* vhh = vhf + (size_t)h * 131072;

  uint4 qr[8];
  {
    const uint4* qp = (const uint4*)(qhf + (size_t)t * 1024 + h * 64);
#pragma unroll
    for (int j = 0; j < 8; j++) qr[j] = qp[j];
  }
  const int4 s4 = sel[((size_t)h << 11) + t];

  const int g16 = lane >> 4;
  const int blk = (g16 == 0) ? s4.x : (g16 == 1) ? s4.y : (g16 == 2) ? s4.z : s4.w;
  const int tok = blk * 16 + (lane & 15);
  {
    float a0 = 0.f, a1 = 0.f, a2 = 0.f, a3 = 0.f;
#pragma unroll
    for (int dc = 0; dc < 8; dc++) {
      const uint4 kk = *(const uint4*)(kT + ((size_t)dc * 2048 + tok) * 8);
      a0 = fdot2u(kk.x, qr[dc].x, a0);
      a1 = fdot2u(kk.y, qr[dc].y, a1);
      a2 = fdot2u(kk.z, qr[dc].z, a2);
      a3 = fdot2u(kk.w, qr[dc].w, a3);
    }
    const float sv_ = (tok <= t) ? ((a0 + a1) + (a2 + a3)) * 0.125f : NEGC;
    const float Ms = wred_max(sv_);
    const float es = __expf(sv_ - Ms);
    ps[w][lane] = es * (1.f / wred_sum(es));
  }

  const int dd = lane & 31, s = lane >> 5;
  const float4* ps4 = (const float4*)ps[w];

  float osx = 0.f, osy = 0.f;
#pragma unroll
  for (int jc = 0; jc < 8; jc++) {
    const float4 p4 = ps4[s * 8 + jc];
    const float pa[4] = {p4.x, p4.y, p4.z, p4.w};
#pragma unroll
    for (int u = 0; u < 4; u++) {
      const int idx = s * 32 + jc * 4 + u;
      const int jb = idx >> 4;
      const int b2 = (jb == 0) ? s4.x : (jb == 1) ? s4.y : (jb == 2) ? s4.z : s4.w;
      const int tok2 = b2 * 16 + (idx & 15);
      const unsigned int vv = *(const unsigned int*)(vhh + (size_t)tok2 * 64 + 2 * dd);
      const h2 v2 = __builtin_bit_cast(h2, vv);
      osx += pa[u] * (float)v2[0];
      osy += pa[u] * (float)v2[1];
    }
  }
  osx += __shfl_xor(osx, 32, 64);
  osy += __shfl_xor(osy, 32, 64);

  {
    const int tw = t - 32 + lane;
    const int twc = min(max(tw, 0), T_LEN - 1);
    float a0 = 0.f, a1 = 0.f, a2 = 0.f, a3 = 0.f;
#pragma unroll
    for (int dc = 0; dc < 8; dc++) {
      const uint4 kk = *(const uint4*)(kT + ((size_t)dc * 2048 + twc) * 8);
      a0 = fdot2u(kk.x, qr[dc].x, a0);
      a1 = fdot2u(kk.y, qr[dc].y, a1);
      a2 = fdot2u(kk.z, qr[dc].z, a2);
      a3 = fdot2u(kk.w, qr[dc].w, a3);
    }
    const float swv = (tw >= 0 && lane <= 32) ? ((a0 + a1) + (a2 + a3)) * 0.125f : NEGC;
    const float Mw = wred_max(swv);
    const float ew = __expf(swv - Mw);
    ps[w][lane] = ew * (1.f / wred_sum(ew));
  }

  float olx = 0.f, oly = 0.f;
#pragma unroll
  for (int j = 0; j < 17; j++) {
    const int idx = s * 17 + j;
    const int idc = min(idx, 32);
    const float p = (idx <= 32) ? ps[w][idc] : 0.f;
    const int tk = min(max(t - 32 + idx, 0), T_LEN - 1);
    const unsigned int vv = *(const unsigned int*)(vhh + (size_t)tk * 64 + 2 * dd);
    const h2 v2 = __builtin_bit_cast(h2, vv);
    olx += p * (float)v2[0];
    oly += p * (float)v2[1];
  }
  olx += __shfl_xor(olx, 32, 64);
  oly += __shfl_xor(oly, 32, 64);

  if (lane < 32) {
    const float2 ocv = *(const float2*)&oc[(size_t)t * 1024 + h * 64 + 2 * dd];
    const float g0 = gates[t * 3 + 0], g1 = gates[t * 3 + 1], g2 = gates[t * 3 + 2];
    const float r0 = g0 * ocv.x + g1 * osx + g2 * olx;
    const float r1 = g0 * ocv.y + g1 * osy + g2 * oly;
    const unsigned int pk = (unsigned int)f32_to_bf16(r0) | ((unsigned int)f32_to_bf16(r1) << 16);
    *(unsigned int*)&outf[(size_t)t * DM + h * 64 + 2 * dd] = pk;
  }
}

// ---------------- launch ----------------
extern "C" void kernel_launch(void* const* d_in, const int* in_sizes, int n_in,
                              void* d_out, int out_size, void* d_ws, size_t ws_size,
                              hipStream_t stream) {
  const float* x   = (const float*)d_in[0];
  const float* Wq  = (const float*)d_in[1];
  const float* Wk  = (const float*)d_in[2];
  const float* Wv  = (const float*)d_in[3];
  const float* Wo  = (const float*)d_in[4];
  const float* Wck = (const float*)d_in[5];
  const float* Wcv = (const float*)d_in[6];
  const float* Wg  = (const float*)d_in[7];
  const float* bg  = (const float*)d_in[8];
  float* out = (float*)d_out;

  float* ws = (float*)d_ws;
  // region A [0,24 MB): C until compress_mfma; then P/oc/outf
  float*          C    = ws;
  unsigned short* P    = (unsigned short*)ws;               // [0,8 MB)
  float*          oc   = ws + 2097152;                      // [8,16 MB)
  unsigned short* outf = (unsigned short*)(ws + 4194304);   // [16,20 MB)
  // region B [24,36 MB): Axx until qkv GEMM; then qh + smalls
  unsigned short* Axx   = (unsigned short*)(ws + 6291456);
  float*          qh    = ws + 6291456;                     // [24,32 MB)
  unsigned short* Wot   = (unsigned short*)(ws + 8388608);  // [32,34 MB)
  unsigned short* kc_hi = (unsigned short*)(ws + 8912896);
  unsigned short* kc_lo = (unsigned short*)(ws + 8978432);
  unsigned short* vcT   = (unsigned short*)(ws + 9043968);
  int4*           sel   = (int4*)(ws + 9109504);
  unsigned short* WckT_hi = (unsigned short*)(ws + 9240576);
  unsigned short* WckT_lo = (unsigned short*)(ws + 9273344);
  unsigned short* WcvT_hi = (unsigned short*)(ws + 9306112);
  unsigned short* WcvT_lo = (unsigned short*)(ws + 9338880);
  float*          gates   = ws + 9371648;
  // region C [36,48 MB): Bqkv until qkv GEMM; then qhf/khfT/vhf f16
  unsigned short* Bqkv = (unsigned short*)(ws + 9437184);   // 2048x3072 bf16, 12 MB
  unsigned short* qhf  = (unsigned short*)(ws + 9437184);   // [36,40 MB)
  unsigned short* khfT = (unsigned short*)(ws + 10485760);  // [40,44 MB)
  unsigned short* vhf  = (unsigned short*)(ws + 11534336);  // [44,48 MB)
  // Wvt scratch lives in d_out (consumed by qkv_gemm before final GEMM writes out)
  unsigned short* Wvt = (unsigned short*)d_out;             // 1024x1024 bf16, 2 MB

  // 1. operand preparation
  cast_x_k<<<2048, 256, 0, stream>>>(x, Axx);
  cast_wt3<<<dim3(32, 32, 2), dim3(32, 8), 0, stream>>>(Wq, Wk, Bqkv);
  cast_wt1<<<dim3(32, 32), dim3(32, 8), 0, stream>>>(Wv, Wvt);

  // 2. merged q|k|v GEMM: 768 blocks (3/CU), 64x128 tiles, swizzled LDS
  qkv_gemm<<<dim3(24, 32), 256, 0, stream>>>(Axx, Bqkv, Wvt, C);

  // 3. reorg + gates (C stays alive for compress); late weight casts
  reorg_qkv<<<6144, 256, 0, stream>>>(C, qh, qhf, khfT, vhf);
  gates_k<<<512, 256, 0, stream>>>(C, Wg, bg, gates);
  cast_wt1<<<dim3(32, 32), dim3(32, 8), 0, stream>>>(Wo, Wot);
  cast_wct<<<dim3(2, 32, 2), dim3(32, 8), 0, stream>>>(Wck, Wcv, WckT_hi, WckT_lo, WcvT_hi, WcvT_lo);

  // 4. compression (MFMA, reads C) + compressed-branch pipeline (C dead after)
  compress_mfma<<<dim3(32, 2), 256, 0, stream>>>(C, WckT_hi, WckT_lo, WcvT_hi, WcvT_lo,
                                                 kc_hi, kc_lo, vcT);
  cscore_k<<<2048, 256, 0, stream>>>(qh, kc_hi, kc_lo, P, sel);
  outc_k<<<256, 256, 0, stream>>>(P, vcT, oc);

  // 5. selected + window + gated combine
  nsa_swl<<<8192, 256, 0, stream>>>(qhf, khfT, vhf, sel, oc, gates, outf);

  // 6. output projection (64x128 tiles, 256 blocks)
  gemm_bt64<<<dim3(8, 32), 256, 0, stream>>>(outf, Wot, out, 1024, 1024, 1024);
}